// Round 1
// baseline (752.363 us; speedup 1.0000x reference)
//
#include <hip/hip_runtime.h>

typedef _Float16 half_t;
typedef half_t h8 __attribute__((ext_vector_type(8)));
typedef float f32x4 __attribute__((ext_vector_type(4)));

__device__ __forceinline__ float lrelu_f(float x){ return x >= 0.f ? x : 0.1f*x; }

enum { EPI_INIT=0, EPI_LRELU=1, EPI_LRELU_L2=2, EPI_L2=3 };

// ---------- weight pre-pack into MFMA B-fragment order (f32 -> f16) ----------
// frag (s, cb): lane l supplies B[k = s*32 + (l>>4)*8 + j][col = cb*16 + (l&15)], j=0..7
__global__ void pack_w_kernel(const float* __restrict__ w, half_t* __restrict__ out, int K, int M){
  int idx = blockIdx.x*256 + threadIdx.x;
  int total = (K/32)*(M/16)*64;
  if (idx >= total) return;
  int lane = idx & 63;
  int t = idx >> 6;
  int CBn = M/16;
  int cb = t % CBn;
  int s  = t / CBn;
  int k0 = s*32 + (lane>>4)*8;
  int c  = cb*16 + (lane&15);
  #pragma unroll
  for (int j=0;j<8;++j) out[(size_t)idx*8 + j] = (half_t)w[(size_t)(k0+j)*M + c];
}

// ---------- unified GEMM: out[n x MOUT] = epi(concat(x0,x1,x2)[n x K] @ W + bias) ----------
template<int K, int MOUT, int NSRC, int EPI>
__global__ __launch_bounds__(256) void gemm_kernel(
  const float* __restrict__ x0, const float* __restrict__ x1, const float* __restrict__ x2,
  const half_t* __restrict__ wp, const float* __restrict__ bias,
  float* __restrict__ out, const float* __restrict__ emb, const int* __restrict__ nid, int n)
{
  constexpr int KS = K/32;
  constexpr int CB = MOUT/16;
  const int lane = threadIdx.x & 63;
  const int wid  = threadIdx.x >> 6;
  const int row0 = blockIdx.x*64 + wid*16;
  const int arow = row0 + (lane & 15);
  const int arowc = arow < n ? arow : n-1;
  const int khi = (lane>>4)*8;

  f32x4 acc[CB];
  #pragma unroll
  for (int cb=0;cb<CB;++cb) acc[cb] = (f32x4){0.f,0.f,0.f,0.f};

  #pragma unroll
  for (int s=0;s<KS;++s){
    int k0 = s*32 + khi;
    const float* xp; long off;
    if constexpr (NSRC==1){ xp = x0; off = (long)arowc*K + k0; }
    else {
      int isrc = k0 >> 6;
      const float* b = x0;
      if constexpr (NSRC>=2){ if(isrc==1) b = x1; }
      if constexpr (NSRC>=3){ if(isrc==2) b = x2; }
      xp = b; off = (long)arowc*64 + (k0 & 63);
    }
    f32x4 a0 = *(const f32x4*)(xp + off);
    f32x4 a1 = *(const f32x4*)(xp + off + 4);
    h8 af;
    #pragma unroll
    for (int j=0;j<4;++j){ af[j]=(half_t)a0[j]; af[j+4]=(half_t)a1[j]; }
    const h8* wrow = (const h8*)wp + (size_t)(s*CB)*64 + lane;
    #pragma unroll
    for (int cb=0;cb<CB;++cb){
      h8 bf = wrow[cb*64];
      acc[cb] = __builtin_amdgcn_mfma_f32_16x16x32_f16(af, bf, acc[cb], 0,0,0);
    }
  }

  const int cgrp = lane >> 4;
  const int ccol = lane & 15;
  #pragma unroll
  for (int r=0;r<4;++r){
    int R = row0 + cgrp*4 + r;
    int Rc = R < n ? R : n-1;
    float v[CB];
    #pragma unroll
    for (int cb=0;cb<CB;++cb){
      float t = acc[cb][r] + bias[cb*16+ccol];
      if constexpr (EPI==EPI_INIT || EPI==EPI_LRELU || EPI==EPI_LRELU_L2) t = lrelu_f(t);
      if constexpr (EPI==EPI_INIT) t += emb[(size_t)(nid[Rc]+1)*64 + cb*16 + ccol];
      v[cb] = t;
    }
    if constexpr (EPI==EPI_LRELU_L2 || EPI==EPI_L2){
      float sq = 0.f;
      #pragma unroll
      for (int cb=0;cb<CB;++cb) sq += v[cb]*v[cb];
      sq += __shfl_xor(sq,1); sq += __shfl_xor(sq,2);
      sq += __shfl_xor(sq,4); sq += __shfl_xor(sq,8);
      float nrm = fmaxf(sqrtf(sq), 1e-6f);
      #pragma unroll
      for (int cb=0;cb<CB;++cb) v[cb] /= nrm;
    }
    if (R < n){
      #pragma unroll
      for (int cb=0;cb<CB;++cb) out[(size_t)R*MOUT + cb*16 + ccol] = v[cb];
    }
  }
}

// ---------- graph machinery ----------
__global__ void hist_kernel(const int* __restrict__ dst, int* __restrict__ deg, int E){
  int i = blockIdx.x*256 + threadIdx.x;
  if (i < E) atomicAdd(&deg[dst[i]], 1);
}

__global__ __launch_bounds__(1024) void scanA_kernel(const int* __restrict__ deg, int* __restrict__ tmp,
                                                     int* __restrict__ totals, int n){
  __shared__ int sm[1024];
  int i = blockIdx.x*1024 + threadIdx.x;
  int v = (i<n)? deg[i] : 0;
  sm[threadIdx.x]=v;
  __syncthreads();
  for (int off=1; off<1024; off<<=1){
    int t = (threadIdx.x>=(unsigned)off)? sm[threadIdx.x-off] : 0;
    __syncthreads();
    sm[threadIdx.x] += t;
    __syncthreads();
  }
  if (i<n) tmp[i] = sm[threadIdx.x]-v;
  if (threadIdx.x==1023) totals[blockIdx.x]=sm[1023];
}

__global__ void scanB_kernel(int* totals, int nb){
  if (threadIdx.x==0 && blockIdx.x==0){
    int run=0;
    for (int b=0;b<nb;++b){ int t=totals[b]; totals[b]=run; run+=t; }
  }
}

__global__ void scanC_kernel(const int* __restrict__ tmp, const int* __restrict__ totals,
                             const int* __restrict__ deg, int* __restrict__ rowptr,
                             int* __restrict__ cursor, float* __restrict__ wden, int n, int E){
  int i = blockIdx.x*256 + threadIdx.x;
  if (i > n) return;
  if (i == n){ rowptr[n]=E; return; }
  int v = tmp[i] + totals[i>>10];
  rowptr[i]=v; cursor[i]=v;
  wden[i] = fmaxf((float)deg[i] - 1.f, 1.f);
}

__global__ void scatter_kernel(const int* __restrict__ src, const int* __restrict__ dst,
                               int* __restrict__ cursor, int* __restrict__ col, int E){
  int i = blockIdx.x*256 + threadIdx.x;
  if (i >= E) return;
  int d = dst[i];
  int pos = atomicAdd(&cursor[d], 1);
  col[pos] = src[i];
}

// wave-per-node CSR gather-sum, layer 0: hagg = (sum - h)/wden, hres = l2norm(hagg)
__global__ __launch_bounds__(256) void segsum0_kernel(const float* __restrict__ h, const int* __restrict__ rowptr,
                               const int* __restrict__ col, const float* __restrict__ wden,
                               float* __restrict__ hagg, float* __restrict__ hres, int n){
  int node = blockIdx.x*4 + (threadIdx.x>>6);
  if (node >= n) return;
  int lane = threadIdx.x & 63;
  int p0 = rowptr[node], p1 = rowptr[node+1];
  float acc = 0.f;
  for (int p=p0; p<p1; ++p){
    int s = col[p];
    acc += h[(size_t)s*64 + lane];
  }
  float a = (acc - h[(size_t)node*64+lane]) / wden[node];
  hagg[(size_t)node*64+lane] = a;
  float sq = a*a;
  #pragma unroll
  for (int m=1;m<64;m<<=1) sq += __shfl_xor(sq,m);
  hres[(size_t)node*64+lane] = a / fmaxf(sqrtf(sq), 1e-6f);
}

// layer 1: dual gather (h and hres); hagg transformed, hsum raw
__global__ __launch_bounds__(256) void segsum1_kernel(const float* __restrict__ h, const float* __restrict__ hres,
                               const int* __restrict__ rowptr, const int* __restrict__ col,
                               const float* __restrict__ wden,
                               float* __restrict__ hagg, float* __restrict__ hsum, int n){
  int node = blockIdx.x*4 + (threadIdx.x>>6);
  if (node >= n) return;
  int lane = threadIdx.x & 63;
  int p0 = rowptr[node], p1 = rowptr[node+1];
  float a=0.f, b=0.f;
  for (int p=p0;p<p1;++p){
    int s = col[p];
    a += h[(size_t)s*64+lane];
    b += hres[(size_t)s*64+lane];
  }
  hagg[(size_t)node*64+lane] = (a - h[(size_t)node*64+lane]) / wden[node];
  hsum[(size_t)node*64+lane] = b;
}

extern "C" void kernel_launch(void* const* d_in, const int* in_sizes, int n_in,
                              void* d_out, int out_size, void* d_ws, size_t ws_size,
                              hipStream_t stream){
  const float* content = (const float*)d_in[0];
  const float* node_emb= (const float*)d_in[1];
  const float* proj_w  = (const float*)d_in[2];
  const float* proj_b  = (const float*)d_in[3];
  const float* c0w1 = (const float*)d_in[4];
  const float* c0b1 = (const float*)d_in[5];
  const float* c0w2 = (const float*)d_in[6];
  const float* c0b2 = (const float*)d_in[7];
  const float* c1w1 = (const float*)d_in[8];
  const float* c1b1 = (const float*)d_in[9];
  const float* c1w2 = (const float*)d_in[10];
  const float* c1b2 = (const float*)d_in[11];
  const int* nid = (const int*)d_in[12];
  const int* src = (const int*)d_in[13];
  const int* dst = (const int*)d_in[14];
  float* out = (float*)d_out;
  const int n = in_sizes[12];     // 100000
  const int E = in_sizes[13];     // 1600000

  char* ws = (char*)d_ws;
  size_t off = 0;
  auto alloc = [&](size_t bytes)->char*{
    char* p = ws + off;
    off = (off + bytes + 255) & ~(size_t)255;
    return p;
  };
  float* h    = (float*)alloc((size_t)n*64*4);
  float* hagg = (float*)alloc((size_t)n*64*4);
  float* hres = (float*)alloc((size_t)n*64*4);
  float* hsum = (float*)alloc((size_t)n*64*4);
  float* hnew = (float*)alloc((size_t)n*64*4);
  float* z    = (float*)alloc((size_t)n*384*4);
  float* wden = (float*)alloc((size_t)n*4);
  int* deg    = (int*)alloc((size_t)n*4);
  int* tmp    = (int*)alloc((size_t)n*4);
  int* cursor = (int*)alloc((size_t)n*4);
  int* rowptr = (int*)alloc((size_t)(n+1)*4);
  int* col    = (int*)alloc((size_t)E*4);
  int* totals = (int*)alloc(1024);
  half_t* wp0 = (half_t*)alloc((size_t)256*64*2);
  half_t* wp1 = (half_t*)alloc((size_t)128*256*2);
  half_t* wp2 = (half_t*)alloc((size_t)256*64*2);
  half_t* wp3 = (half_t*)alloc((size_t)192*384*2);
  half_t* wp4 = (half_t*)alloc((size_t)384*64*2);

  hipMemsetAsync(deg, 0, (size_t)n*4, stream);

  auto packgrid = [](int K, int M){ return dim3((K*M/8 + 255)/256); };
  pack_w_kernel<<<packgrid(256,64), 256, 0, stream>>>(proj_w, wp0, 256, 64);
  pack_w_kernel<<<packgrid(128,256),256, 0, stream>>>(c0w1, wp1, 128, 256);
  pack_w_kernel<<<packgrid(256,64), 256, 0, stream>>>(c0w2, wp2, 256, 64);
  pack_w_kernel<<<packgrid(192,384),256, 0, stream>>>(c1w1, wp3, 192, 384);
  pack_w_kernel<<<packgrid(384,64), 256, 0, stream>>>(c1w2, wp4, 384, 64);

  const int egrid = (E + 255)/256;
  const int rgrid = (n + 63)/64;
  const int nb1024 = (n + 1023)/1024;

  // h = node_emb[nid+1] + lrelu(content @ proj_w + proj_b)
  gemm_kernel<256,64,1,EPI_INIT><<<rgrid,256,0,stream>>>(content,nullptr,nullptr, wp0, proj_b, h, node_emb, nid, n);

  // CSR build
  hist_kernel<<<egrid,256,0,stream>>>(dst, deg, E);
  scanA_kernel<<<nb1024,1024,0,stream>>>(deg, tmp, totals, n);
  scanB_kernel<<<1,64,0,stream>>>(totals, nb1024);
  scanC_kernel<<<(n+256)/256 + 1,256,0,stream>>>(tmp, totals, deg, rowptr, cursor, wden, n, E);
  scatter_kernel<<<egrid,256,0,stream>>>(src, dst, cursor, col, E);

  // layer 0
  segsum0_kernel<<<(n+3)/4,256,0,stream>>>(h, rowptr, col, wden, hagg, hres, n);
  gemm_kernel<128,256,2,EPI_LRELU><<<rgrid,256,0,stream>>>(h, hagg, nullptr, wp1, c0b1, z, nullptr, nullptr, n);
  gemm_kernel<256,64,1,EPI_LRELU_L2><<<rgrid,256,0,stream>>>(z, nullptr, nullptr, wp2, c0b2, hnew, nullptr, nullptr, n);

  // layer 1
  segsum1_kernel<<<(n+3)/4,256,0,stream>>>(hnew, hres, rowptr, col, wden, hagg, hsum, n);
  gemm_kernel<192,384,3,EPI_LRELU><<<rgrid,256,0,stream>>>(hnew, hagg, hsum, wp3, c1b1, z, nullptr, nullptr, n);
  gemm_kernel<384,64,1,EPI_L2><<<rgrid,256,0,stream>>>(z, nullptr, nullptr, wp4, c1b2, out, nullptr, nullptr, n);
}

// Round 2
// 526.661 us; speedup vs baseline: 1.4286x; 1.4286x over previous
//
#include <hip/hip_runtime.h>

typedef _Float16 half_t;
typedef half_t h8 __attribute__((ext_vector_type(8)));
typedef float f32x4 __attribute__((ext_vector_type(4)));
typedef unsigned int uint;

__device__ __forceinline__ float lrelu_f(float x){ return x >= 0.f ? x : 0.1f*x; }

__device__ __forceinline__ float2 unpack_h2(uint v){
  half_t lo = __builtin_bit_cast(half_t, (unsigned short)(v & 0xffffu));
  half_t hi = __builtin_bit_cast(half_t, (unsigned short)(v >> 16));
  return make_float2((float)lo, (float)hi);
}
__device__ __forceinline__ uint pack_h2(float a, float b){
  unsigned short lo = __builtin_bit_cast(unsigned short, (half_t)a);
  unsigned short hi = __builtin_bit_cast(unsigned short, (half_t)b);
  return (uint)lo | ((uint)hi << 16);
}

enum { EPI_INIT=0, EPI_LRELU=1, EPI_LRELU_L2=2, EPI_L2=3 };

// ---------- weight pre-pack into MFMA B-fragment order (f32 -> f16) ----------
// frag (s, cb): lane l supplies B[k = s*32 + (l>>4)*8 + j][col = cb*16 + (l&15)], j=0..7
__global__ void pack_w_kernel(const float* __restrict__ w, half_t* __restrict__ out, int K, int M){
  int idx = blockIdx.x*256 + threadIdx.x;
  int total = (K/32)*(M/16)*64;
  if (idx >= total) return;
  int lane = idx & 63;
  int t = idx >> 6;
  int CBn = M/16;
  int cb = t % CBn;
  int s  = t / CBn;
  int k0 = s*32 + (lane>>4)*8;
  int c  = cb*16 + (lane&15);
  #pragma unroll
  for (int j=0;j<8;++j) out[(size_t)idx*8 + j] = (half_t)w[(size_t)(k0+j)*M + c];
}

// ---------- unified GEMM: out[n x MOUT] = epi(concat(x...)[n x K] @ W + bias) ----------
template<int K, int MOUT, int NSRC, int EPI, bool AF16, bool OUTF16>
__global__ __launch_bounds__(256) void gemm_kernel(
  const void* __restrict__ x0v, const void* __restrict__ x1v, const void* __restrict__ x2v,
  int st0, int st1, int st2,
  const half_t* __restrict__ wp, const float* __restrict__ bias,
  void* __restrict__ outv, int ost,
  const float* __restrict__ emb, const int* __restrict__ nid, int n)
{
  constexpr int KS = K/32;
  constexpr int CB = MOUT/16;
  const int lane = threadIdx.x & 63;
  const int wid  = threadIdx.x >> 6;
  const int row0 = blockIdx.x*64 + wid*16;
  const int arow = row0 + (lane & 15);
  const int arowc = arow < n ? arow : n-1;
  const int khi = (lane>>4)*8;

  f32x4 acc[CB];
  #pragma unroll
  for (int cb=0;cb<CB;++cb) acc[cb] = (f32x4){0.f,0.f,0.f,0.f};

  #pragma unroll
  for (int s=0;s<KS;++s){
    int k0 = s*32 + khi;
    h8 af;
    if constexpr (AF16){
      if constexpr (NSRC==1){
        const half_t* xp = (const half_t*)x0v;
        af = *(const h8*)(xp + (size_t)arowc*st0 + k0);
      } else {
        int isrc = k0 >> 6;
        const half_t* p = (const half_t*)x0v; int st = st0;
        if constexpr (NSRC>=2){ if(isrc==1){ p=(const half_t*)x1v; st=st1; } }
        if constexpr (NSRC>=3){ if(isrc==2){ p=(const half_t*)x2v; st=st2; } }
        af = *(const h8*)(p + (size_t)arowc*st + (k0 & 63));
      }
    } else {
      const float* xp = (const float*)x0v;
      f32x4 a0 = *(const f32x4*)(xp + (size_t)arowc*st0 + k0);
      f32x4 a1 = *(const f32x4*)(xp + (size_t)arowc*st0 + k0 + 4);
      #pragma unroll
      for (int j=0;j<4;++j){ af[j]=(half_t)a0[j]; af[j+4]=(half_t)a1[j]; }
    }
    const h8* wrow = (const h8*)wp + (size_t)(s*CB)*64 + lane;
    #pragma unroll
    for (int cb=0;cb<CB;++cb){
      h8 bf = wrow[cb*64];
      acc[cb] = __builtin_amdgcn_mfma_f32_16x16x32_f16(af, bf, acc[cb], 0,0,0);
    }
  }

  const int cgrp = lane >> 4;
  const int ccol = lane & 15;
  #pragma unroll
  for (int r=0;r<4;++r){
    int R = row0 + cgrp*4 + r;
    int Rc = R < n ? R : n-1;
    float v[CB];
    #pragma unroll
    for (int cb=0;cb<CB;++cb){
      float t = acc[cb][r] + bias[cb*16+ccol];
      if constexpr (EPI==EPI_INIT || EPI==EPI_LRELU || EPI==EPI_LRELU_L2) t = lrelu_f(t);
      if constexpr (EPI==EPI_INIT) t += emb[(size_t)(nid[Rc]+1)*64 + cb*16 + ccol];
      v[cb] = t;
    }
    if constexpr (EPI==EPI_LRELU_L2 || EPI==EPI_L2){
      float sq = 0.f;
      #pragma unroll
      for (int cb=0;cb<CB;++cb) sq += v[cb]*v[cb];
      sq += __shfl_xor(sq,1); sq += __shfl_xor(sq,2);
      sq += __shfl_xor(sq,4); sq += __shfl_xor(sq,8);
      float inv = 1.f / fmaxf(sqrtf(sq), 1e-6f);
      #pragma unroll
      for (int cb=0;cb<CB;++cb) v[cb] *= inv;
    }
    if (R < n){
      #pragma unroll
      for (int cb=0;cb<CB;++cb){
        if constexpr (OUTF16)
          ((half_t*)outv)[(size_t)R*ost + cb*16 + ccol] = (half_t)v[cb];
        else
          ((float*)outv)[(size_t)R*ost + cb*16 + ccol] = v[cb];
      }
    }
  }
}

// ---------- graph machinery ----------
__global__ void hist_kernel(const int* __restrict__ dst, int* __restrict__ deg, int E){
  int i = blockIdx.x*256 + threadIdx.x;
  if (i < E) atomicAdd(&deg[dst[i]], 1);
}

__global__ __launch_bounds__(1024) void scanA_kernel(const int* __restrict__ deg, int* __restrict__ tmp,
                                                     int* __restrict__ totals, int n){
  __shared__ int sm[1024];
  int i = blockIdx.x*1024 + threadIdx.x;
  int v = (i<n)? deg[i] : 0;
  sm[threadIdx.x]=v;
  __syncthreads();
  for (int off=1; off<1024; off<<=1){
    int t = (threadIdx.x>=(unsigned)off)? sm[threadIdx.x-off] : 0;
    __syncthreads();
    sm[threadIdx.x] += t;
    __syncthreads();
  }
  if (i<n) tmp[i] = sm[threadIdx.x]-v;
  if (threadIdx.x==1023) totals[blockIdx.x]=sm[1023];
}

__global__ void scanB_kernel(int* totals, int nb){
  if (threadIdx.x==0 && blockIdx.x==0){
    int run=0;
    for (int b=0;b<nb;++b){ int t=totals[b]; totals[b]=run; run+=t; }
  }
}

__global__ void scanC_kernel(const int* __restrict__ tmp, const int* __restrict__ totals,
                             const int* __restrict__ deg, int* __restrict__ rowptr,
                             int* __restrict__ cursor, float* __restrict__ wden, int n, int E){
  int i = blockIdx.x*256 + threadIdx.x;
  if (i > n) return;
  if (i == n){ rowptr[n]=E; return; }
  int v = tmp[i] + totals[i>>10];
  rowptr[i]=v; cursor[i]=v;
  wden[i] = fmaxf((float)deg[i] - 1.f, 1.f);
}

__global__ void scatter_kernel(const int* __restrict__ src, const int* __restrict__ dst,
                               int* __restrict__ cursor, int* __restrict__ col, int E){
  int i = blockIdx.x*256 + threadIdx.x;
  if (i >= E) return;
  int d = dst[i];
  int pos = atomicAdd(&cursor[d], 1);
  col[pos] = src[i];
}

// layer-0 gather: h rows are 128B (64 f16 = 32 uint). 2 edges per wave:
// lane = j*32+e, j = edge-in-pair, e = uint index. hagg=(sum-h)/wden (f16),
// hres = l2norm(hagg) written into second half of combined hc rows.
__global__ __launch_bounds__(256) void segsum0_kernel(const uint* __restrict__ hu, const int* __restrict__ rowptr,
                               const int* __restrict__ col, const float* __restrict__ wden,
                               uint* __restrict__ hagg, uint* __restrict__ hc, int n){
  int node = blockIdx.x*4 + (threadIdx.x>>6);
  if (node >= n) return;
  int lane = threadIdx.x & 63;
  int e = lane & 31, j = lane >> 5;
  int p0 = rowptr[node], p1 = rowptr[node+1];
  float a0=0.f, a1=0.f;
  #pragma unroll 4
  for (int p = p0 + j; p < p1; p += 2){
    int c = col[p];
    float2 v = unpack_h2(hu[(size_t)c*32 + e]);
    a0 += v.x; a1 += v.y;
  }
  a0 += __shfl_xor(a0, 32);
  a1 += __shfl_xor(a1, 32);
  float2 hv = unpack_h2(hu[(size_t)node*32 + e]);
  float wd = wden[node];
  a0 = (a0 - hv.x) / wd;
  a1 = (a1 - hv.y) / wd;
  float sq = a0*a0 + a1*a1;
  #pragma unroll
  for (int m=1;m<32;m<<=1) sq += __shfl_xor(sq, m);
  float inv = 1.f / fmaxf(sqrtf(sq), 1e-6f);
  if (j == 0){
    hagg[(size_t)node*32 + e] = pack_h2(a0, a1);
    hc[(size_t)node*64 + 32 + e] = pack_h2(a0*inv, a1*inv);
  }
}

// layer-1 gather: combined hc rows are 256B (hnew f16 x64 || hres f16 x64).
// One node per wave; lanes 0..31 accumulate hnew-sum, 32..63 hres-sum.
__global__ __launch_bounds__(256) void segsum1_kernel(const uint* __restrict__ hcu, const int* __restrict__ rowptr,
                               const int* __restrict__ col, const float* __restrict__ wden,
                               uint* __restrict__ hagg, uint* __restrict__ hsum, int n){
  int node = blockIdx.x*4 + (threadIdx.x>>6);
  if (node >= n) return;
  int lane = threadIdx.x & 63;
  int p0 = rowptr[node], p1 = rowptr[node+1];
  float a0=0.f, a1=0.f;
  #pragma unroll 4
  for (int p=p0; p<p1; ++p){
    int c = col[p];
    float2 v = unpack_h2(hcu[(size_t)c*64 + lane]);
    a0 += v.x; a1 += v.y;
  }
  if (lane < 32){
    float2 hv = unpack_h2(hcu[(size_t)node*64 + lane]);
    float wd = wden[node];
    hagg[(size_t)node*32 + lane] = pack_h2((a0 - hv.x)/wd, (a1 - hv.y)/wd);
  } else {
    hsum[(size_t)node*32 + (lane-32)] = pack_h2(a0, a1);
  }
}

extern "C" void kernel_launch(void* const* d_in, const int* in_sizes, int n_in,
                              void* d_out, int out_size, void* d_ws, size_t ws_size,
                              hipStream_t stream){
  const float* content = (const float*)d_in[0];
  const float* node_emb= (const float*)d_in[1];
  const float* proj_w  = (const float*)d_in[2];
  const float* proj_b  = (const float*)d_in[3];
  const float* c0w1 = (const float*)d_in[4];
  const float* c0b1 = (const float*)d_in[5];
  const float* c0w2 = (const float*)d_in[6];
  const float* c0b2 = (const float*)d_in[7];
  const float* c1w1 = (const float*)d_in[8];
  const float* c1b1 = (const float*)d_in[9];
  const float* c1w2 = (const float*)d_in[10];
  const float* c1b2 = (const float*)d_in[11];
  const int* nid = (const int*)d_in[12];
  const int* src = (const int*)d_in[13];
  const int* dst = (const int*)d_in[14];
  float* out = (float*)d_out;
  const int n = in_sizes[12];     // 100000
  const int E = in_sizes[13];     // 1600000

  char* ws = (char*)d_ws;
  size_t off = 0;
  auto alloc = [&](size_t bytes)->char*{
    char* p = ws + off;
    off = (off + bytes + 255) & ~(size_t)255;
    return p;
  };
  half_t* h0   = (half_t*)alloc((size_t)n*64*2);    // init h, f16, stride 64
  half_t* hc   = (half_t*)alloc((size_t)n*128*2);   // [hnew(64) || hres(64)] f16, stride 128
  half_t* hagg0= (half_t*)alloc((size_t)n*64*2);
  half_t* hagg1= (half_t*)alloc((size_t)n*64*2);
  half_t* hsum1= (half_t*)alloc((size_t)n*64*2);
  half_t* z0   = (half_t*)alloc((size_t)n*256*2);
  half_t* z1   = (half_t*)alloc((size_t)n*384*2);
  float* wden = (float*)alloc((size_t)n*4);
  int* deg    = (int*)alloc((size_t)n*4);
  int* tmp    = (int*)alloc((size_t)n*4);
  int* cursor = (int*)alloc((size_t)n*4);
  int* rowptr = (int*)alloc((size_t)(n+1)*4);
  int* col    = (int*)alloc((size_t)E*4);
  int* totals = (int*)alloc(1024);
  half_t* wp0 = (half_t*)alloc((size_t)256*64*2);
  half_t* wp1 = (half_t*)alloc((size_t)128*256*2);
  half_t* wp2 = (half_t*)alloc((size_t)256*64*2);
  half_t* wp3 = (half_t*)alloc((size_t)192*384*2);
  half_t* wp4 = (half_t*)alloc((size_t)384*64*2);

  hipMemsetAsync(deg, 0, (size_t)n*4, stream);

  auto packgrid = [](int K, int M){ return dim3((K*M/8 + 255)/256); };
  pack_w_kernel<<<packgrid(256,64), 256, 0, stream>>>(proj_w, wp0, 256, 64);
  pack_w_kernel<<<packgrid(128,256),256, 0, stream>>>(c0w1, wp1, 128, 256);
  pack_w_kernel<<<packgrid(256,64), 256, 0, stream>>>(c0w2, wp2, 256, 64);
  pack_w_kernel<<<packgrid(192,384),256, 0, stream>>>(c1w1, wp3, 192, 384);
  pack_w_kernel<<<packgrid(384,64), 256, 0, stream>>>(c1w2, wp4, 384, 64);

  const int egrid = (E + 255)/256;
  const int rgrid = (n + 63)/64;
  const int nb1024 = (n + 1023)/1024;

  // h0 = node_emb[nid+1] + lrelu(content @ proj_w + proj_b)   (f32 A, f16 out)
  gemm_kernel<256,64,1,EPI_INIT,false,true><<<rgrid,256,0,stream>>>(
      content,nullptr,nullptr, 256,0,0, wp0, proj_b, h0, 64, node_emb, nid, n);

  // CSR build
  hist_kernel<<<egrid,256,0,stream>>>(dst, deg, E);
  scanA_kernel<<<nb1024,1024,0,stream>>>(deg, tmp, totals, n);
  scanB_kernel<<<1,64,0,stream>>>(totals, nb1024);
  scanC_kernel<<<(n+256)/256 + 1,256,0,stream>>>(tmp, totals, deg, rowptr, cursor, wden, n, E);
  scatter_kernel<<<egrid,256,0,stream>>>(src, dst, cursor, col, E);

  // layer 0
  segsum0_kernel<<<(n+3)/4,256,0,stream>>>((const uint*)h0, rowptr, col, wden,
                                           (uint*)hagg0, (uint*)hc, n);
  gemm_kernel<128,256,2,EPI_LRELU,true,true><<<rgrid,256,0,stream>>>(
      h0, hagg0, nullptr, 64,64,0, wp1, c0b1, z0, 256, nullptr, nullptr, n);
  gemm_kernel<256,64,1,EPI_LRELU_L2,true,true><<<rgrid,256,0,stream>>>(
      z0, nullptr, nullptr, 256,0,0, wp2, c0b2, hc, 128, nullptr, nullptr, n);  // hnew -> hc[:,0:64]

  // layer 1
  segsum1_kernel<<<(n+3)/4,256,0,stream>>>((const uint*)hc, rowptr, col, wden,
                                           (uint*)hagg1, (uint*)hsum1, n);
  gemm_kernel<192,384,3,EPI_LRELU,true,true><<<rgrid,256,0,stream>>>(
      hc, hagg1, hsum1, 128,64,64, wp3, c1b1, z1, 384, nullptr, nullptr, n);
  gemm_kernel<384,64,1,EPI_L2,true,false><<<rgrid,256,0,stream>>>(
      z1, nullptr, nullptr, 384,0,0, wp4, c1b2, out, 64, nullptr, nullptr, n);
}

// Round 3
// 457.568 us; speedup vs baseline: 1.6443x; 1.1510x over previous
//
#include <hip/hip_runtime.h>

typedef _Float16 half_t;
typedef half_t h8 __attribute__((ext_vector_type(8)));
typedef float f32x4 __attribute__((ext_vector_type(4)));
typedef unsigned int uint;

__device__ __forceinline__ float lrelu_f(float x){ return x >= 0.f ? x : 0.1f*x; }

__device__ __forceinline__ float2 unpack_h2(uint v){
  half_t lo = __builtin_bit_cast(half_t, (unsigned short)(v & 0xffffu));
  half_t hi = __builtin_bit_cast(half_t, (unsigned short)(v >> 16));
  return make_float2((float)lo, (float)hi);
}
__device__ __forceinline__ uint pack_h2(float a, float b){
  unsigned short lo = __builtin_bit_cast(unsigned short, (half_t)a);
  unsigned short hi = __builtin_bit_cast(unsigned short, (half_t)b);
  return (uint)lo | ((uint)hi << 16);
}

enum { EPI_INIT=0, EPI_LRELU=1, EPI_LRELU_L2=2, EPI_L2=3 };

// ---------- weight pre-pack into MFMA B-fragment order (f32 -> f16) ----------
__global__ void pack_w_kernel(const float* __restrict__ w, half_t* __restrict__ out, int K, int M){
  int idx = blockIdx.x*256 + threadIdx.x;
  int total = (K/32)*(M/16)*64;
  if (idx >= total) return;
  int lane = idx & 63;
  int t = idx >> 6;
  int CBn = M/16;
  int cb = t % CBn;
  int s  = t / CBn;
  int k0 = s*32 + (lane>>4)*8;
  int c  = cb*16 + (lane&15);
  #pragma unroll
  for (int j=0;j<8;++j) out[(size_t)idx*8 + j] = (half_t)w[(size_t)(k0+j)*M + c];
}

// ---------- unified GEMM ----------
template<int K, int MOUT, int NSRC, int EPI, bool AF16, bool OUTF16>
__global__ __launch_bounds__(256) void gemm_kernel(
  const void* __restrict__ x0v, const void* __restrict__ x1v, const void* __restrict__ x2v,
  int st0, int st1, int st2,
  const half_t* __restrict__ wp, const float* __restrict__ bias,
  void* __restrict__ outv, int ost,
  const float* __restrict__ emb, const int* __restrict__ nid, int n)
{
  constexpr int KS = K/32;
  constexpr int CB = MOUT/16;
  const int lane = threadIdx.x & 63;
  const int wid  = threadIdx.x >> 6;
  const int row0 = blockIdx.x*64 + wid*16;
  const int arow = row0 + (lane & 15);
  const int arowc = arow < n ? arow : n-1;
  const int khi = (lane>>4)*8;

  f32x4 acc[CB];
  #pragma unroll
  for (int cb=0;cb<CB;++cb) acc[cb] = (f32x4){0.f,0.f,0.f,0.f};

  #pragma unroll
  for (int s=0;s<KS;++s){
    int k0 = s*32 + khi;
    h8 af;
    if constexpr (AF16){
      if constexpr (NSRC==1){
        const half_t* xp = (const half_t*)x0v;
        af = *(const h8*)(xp + (size_t)arowc*st0 + k0);
      } else {
        int isrc = k0 >> 6;
        const half_t* p = (const half_t*)x0v; int st = st0;
        if constexpr (NSRC>=2){ if(isrc==1){ p=(const half_t*)x1v; st=st1; } }
        if constexpr (NSRC>=3){ if(isrc==2){ p=(const half_t*)x2v; st=st2; } }
        af = *(const h8*)(p + (size_t)arowc*st + (k0 & 63));
      }
    } else {
      const float* xp = (const float*)x0v;
      f32x4 a0 = *(const f32x4*)(xp + (size_t)arowc*st0 + k0);
      f32x4 a1 = *(const f32x4*)(xp + (size_t)arowc*st0 + k0 + 4);
      #pragma unroll
      for (int j=0;j<4;++j){ af[j]=(half_t)a0[j]; af[j+4]=(half_t)a1[j]; }
    }
    const h8* wrow = (const h8*)wp + (size_t)(s*CB)*64 + lane;
    #pragma unroll
    for (int cb=0;cb<CB;++cb){
      h8 bf = wrow[cb*64];
      acc[cb] = __builtin_amdgcn_mfma_f32_16x16x32_f16(af, bf, acc[cb], 0,0,0);
    }
  }

  const int cgrp = lane >> 4;
  const int ccol = lane & 15;
  #pragma unroll
  for (int r=0;r<4;++r){
    int R = row0 + cgrp*4 + r;
    int Rc = R < n ? R : n-1;
    float v[CB];
    #pragma unroll
    for (int cb=0;cb<CB;++cb){
      float t = acc[cb][r] + bias[cb*16+ccol];
      if constexpr (EPI==EPI_INIT || EPI==EPI_LRELU || EPI==EPI_LRELU_L2) t = lrelu_f(t);
      if constexpr (EPI==EPI_INIT) t += emb[(size_t)(nid[Rc]+1)*64 + cb*16 + ccol];
      v[cb] = t;
    }
    if constexpr (EPI==EPI_LRELU_L2 || EPI==EPI_L2){
      float sq = 0.f;
      #pragma unroll
      for (int cb=0;cb<CB;++cb) sq += v[cb]*v[cb];
      sq += __shfl_xor(sq,1); sq += __shfl_xor(sq,2);
      sq += __shfl_xor(sq,4); sq += __shfl_xor(sq,8);
      float inv = 1.f / fmaxf(sqrtf(sq), 1e-6f);
      #pragma unroll
      for (int cb=0;cb<CB;++cb) v[cb] *= inv;
    }
    if (R < n){
      #pragma unroll
      for (int cb=0;cb<CB;++cb){
        if constexpr (OUTF16)
          ((half_t*)outv)[(size_t)R*ost + cb*16 + ccol] = (half_t)v[cb];
        else
          ((float*)outv)[(size_t)R*ost + cb*16 + ccol] = v[cb];
      }
    }
  }
}

// ---------- graph machinery ----------
__global__ void hist_kernel(const int* __restrict__ dst, int* __restrict__ deg, int E){
  int i = blockIdx.x*256 + threadIdx.x;
  if (i < E) atomicAdd(&deg[dst[i]], 1);
}

__global__ __launch_bounds__(1024) void scanA_kernel(const int* __restrict__ deg, int* __restrict__ tmp,
                                                     int* __restrict__ totals, int n){
  __shared__ int sm[1024];
  int i = blockIdx.x*1024 + threadIdx.x;
  int v = (i<n)? deg[i] : 0;
  sm[threadIdx.x]=v;
  __syncthreads();
  for (int off=1; off<1024; off<<=1){
    int t = (threadIdx.x>=(unsigned)off)? sm[threadIdx.x-off] : 0;
    __syncthreads();
    sm[threadIdx.x] += t;
    __syncthreads();
  }
  if (i<n) tmp[i] = sm[threadIdx.x]-v;
  if (threadIdx.x==1023) totals[blockIdx.x]=sm[1023];
}

// parallel exclusive scan of totals (nb <= 1024)
__global__ __launch_bounds__(1024) void scanB_kernel(int* totals, int nb){
  __shared__ int sm[1024];
  int v = (threadIdx.x < (unsigned)nb) ? totals[threadIdx.x] : 0;
  sm[threadIdx.x]=v;
  __syncthreads();
  for (int off=1; off<1024; off<<=1){
    int t = (threadIdx.x>=(unsigned)off)? sm[threadIdx.x-off] : 0;
    __syncthreads();
    sm[threadIdx.x] += t;
    __syncthreads();
  }
  if (threadIdx.x < (unsigned)nb) totals[threadIdx.x] = sm[threadIdx.x]-v;
}

__global__ void scanC_kernel(const int* __restrict__ tmp, const int* __restrict__ totals,
                             const int* __restrict__ deg, int* __restrict__ rowptr,
                             int* __restrict__ cursor, float* __restrict__ wden, int n, int E){
  int i = blockIdx.x*256 + threadIdx.x;
  if (i > n) return;
  if (i == n){ rowptr[n]=E; return; }
  int v = tmp[i] + totals[i>>10];
  rowptr[i]=v; cursor[i]=v;
  wden[i] = fmaxf((float)deg[i] - 1.f, 1.f);
}

// XCD-partitioned scatter: block b -> edge chunk (b>>3), dst range (b&7).
// Consecutive blocks round-robin across XCDs, so each col/cursor region is
// written by (mostly) one XCD -> no cross-XCD line ping-pong / writeback blowup.
template<int IT>
__global__ __launch_bounds__(256) void scatter_kernel(const int* __restrict__ src, const int* __restrict__ dst,
                               int* __restrict__ cursor, int* __restrict__ col, int E, int n){
  int part = blockIdx.x & 7;
  long base = (long)(blockIdx.x >> 3) * (256*IT);
  int lo = (int)((long)n * part / 8);
  int hi = (int)((long)n * (part+1) / 8);
  #pragma unroll
  for (int it=0; it<IT; ++it){
    long i = base + it*256 + threadIdx.x;
    if (i < E){
      int d = dst[i];
      if (d >= lo && d < hi){
        int pos = atomicAdd(&cursor[d], 1);
        col[pos] = src[i];
      }
    }
  }
}

// layer-0 gather: h rows 128B = 8 lanes x 16B. 8 edge-groups per wave.
__global__ __launch_bounds__(256) void segsum0_kernel(const uint* __restrict__ hu, const int* __restrict__ rowptr,
                               const int* __restrict__ col, const float* __restrict__ wden,
                               uint* __restrict__ hagg, uint* __restrict__ hc, int n){
  int node = blockIdx.x*4 + (threadIdx.x>>6);
  if (node >= n) return;
  int lane = threadIdx.x & 63;
  int g = lane >> 3, l = lane & 7;
  int p0 = rowptr[node], p1 = rowptr[node+1];
  float a[8] = {0,0,0,0,0,0,0,0};
  for (int p = p0 + g; p < p1; p += 8){
    int c = col[p];
    uint4 v = *(const uint4*)(hu + (size_t)c*32 + l*4);
    float2 f0=unpack_h2(v.x), f1=unpack_h2(v.y), f2=unpack_h2(v.z), f3=unpack_h2(v.w);
    a[0]+=f0.x; a[1]+=f0.y; a[2]+=f1.x; a[3]+=f1.y;
    a[4]+=f2.x; a[5]+=f2.y; a[6]+=f3.x; a[7]+=f3.y;
  }
  #pragma unroll
  for (int j=0;j<8;++j){
    a[j] += __shfl_xor(a[j], 8);
    a[j] += __shfl_xor(a[j], 16);
    a[j] += __shfl_xor(a[j], 32);
  }
  uint4 hv4 = *(const uint4*)(hu + (size_t)node*32 + l*4);
  float2 b0=unpack_h2(hv4.x), b1=unpack_h2(hv4.y), b2=unpack_h2(hv4.z), b3=unpack_h2(hv4.w);
  float hv[8] = {b0.x,b0.y,b1.x,b1.y,b2.x,b2.y,b3.x,b3.y};
  float iwd = 1.f / wden[node];
  float sq = 0.f;
  #pragma unroll
  for (int j=0;j<8;++j){ a[j] = (a[j]-hv[j])*iwd; sq += a[j]*a[j]; }
  sq += __shfl_xor(sq,1); sq += __shfl_xor(sq,2); sq += __shfl_xor(sq,4);
  float inv = 1.f / fmaxf(sqrtf(sq), 1e-6f);
  if (g == 0){
    uint4 oa, oh;
    oa.x = pack_h2(a[0],a[1]); oa.y = pack_h2(a[2],a[3]);
    oa.z = pack_h2(a[4],a[5]); oa.w = pack_h2(a[6],a[7]);
    oh.x = pack_h2(a[0]*inv,a[1]*inv); oh.y = pack_h2(a[2]*inv,a[3]*inv);
    oh.z = pack_h2(a[4]*inv,a[5]*inv); oh.w = pack_h2(a[6]*inv,a[7]*inv);
    *(uint4*)(hagg + (size_t)node*32 + l*4) = oa;
    *(uint4*)(hc + (size_t)node*64 + 32 + l*4) = oh;
  }
}

// layer-1 gather: hc rows 256B = 16 lanes x 16B. 4 edge-groups per wave.
__global__ __launch_bounds__(256) void segsum1_kernel(const uint* __restrict__ hcu, const int* __restrict__ rowptr,
                               const int* __restrict__ col, const float* __restrict__ wden,
                               uint* __restrict__ hagg, uint* __restrict__ hsum, int n){
  int node = blockIdx.x*4 + (threadIdx.x>>6);
  if (node >= n) return;
  int lane = threadIdx.x & 63;
  int g = lane >> 4, l = lane & 15;
  int p0 = rowptr[node], p1 = rowptr[node+1];
  float a[8] = {0,0,0,0,0,0,0,0};
  for (int p = p0 + g; p < p1; p += 4){
    int c = col[p];
    uint4 v = *(const uint4*)(hcu + (size_t)c*64 + l*4);
    float2 f0=unpack_h2(v.x), f1=unpack_h2(v.y), f2=unpack_h2(v.z), f3=unpack_h2(v.w);
    a[0]+=f0.x; a[1]+=f0.y; a[2]+=f1.x; a[3]+=f1.y;
    a[4]+=f2.x; a[5]+=f2.y; a[6]+=f3.x; a[7]+=f3.y;
  }
  #pragma unroll
  for (int j=0;j<8;++j){
    a[j] += __shfl_xor(a[j], 16);
    a[j] += __shfl_xor(a[j], 32);
  }
  if (g == 0){
    if (l < 8){
      // hnew window: subtract own h, divide by wden
      uint4 hv4 = *(const uint4*)(hcu + (size_t)node*64 + l*4);
      float2 b0=unpack_h2(hv4.x), b1=unpack_h2(hv4.y), b2=unpack_h2(hv4.z), b3=unpack_h2(hv4.w);
      float hv[8] = {b0.x,b0.y,b1.x,b1.y,b2.x,b2.y,b3.x,b3.y};
      float iwd = 1.f / wden[node];
      uint4 o;
      o.x = pack_h2((a[0]-hv[0])*iwd,(a[1]-hv[1])*iwd);
      o.y = pack_h2((a[2]-hv[2])*iwd,(a[3]-hv[3])*iwd);
      o.z = pack_h2((a[4]-hv[4])*iwd,(a[5]-hv[5])*iwd);
      o.w = pack_h2((a[6]-hv[6])*iwd,(a[7]-hv[7])*iwd);
      *(uint4*)(hagg + (size_t)node*32 + l*4) = o;
    } else {
      uint4 o;
      o.x = pack_h2(a[0],a[1]); o.y = pack_h2(a[2],a[3]);
      o.z = pack_h2(a[4],a[5]); o.w = pack_h2(a[6],a[7]);
      *(uint4*)(hsum + (size_t)node*32 + (l-8)*4) = o;
    }
  }
}

extern "C" void kernel_launch(void* const* d_in, const int* in_sizes, int n_in,
                              void* d_out, int out_size, void* d_ws, size_t ws_size,
                              hipStream_t stream){
  const float* content = (const float*)d_in[0];
  const float* node_emb= (const float*)d_in[1];
  const float* proj_w  = (const float*)d_in[2];
  const float* proj_b  = (const float*)d_in[3];
  const float* c0w1 = (const float*)d_in[4];
  const float* c0b1 = (const float*)d_in[5];
  const float* c0w2 = (const float*)d_in[6];
  const float* c0b2 = (const float*)d_in[7];
  const float* c1w1 = (const float*)d_in[8];
  const float* c1b1 = (const float*)d_in[9];
  const float* c1w2 = (const float*)d_in[10];
  const float* c1b2 = (const float*)d_in[11];
  const int* nid = (const int*)d_in[12];
  const int* src = (const int*)d_in[13];
  const int* dst = (const int*)d_in[14];
  float* out = (float*)d_out;
  const int n = in_sizes[12];     // 100000
  const int E = in_sizes[13];     // 1600000

  char* ws = (char*)d_ws;
  size_t off = 0;
  auto alloc = [&](size_t bytes)->char*{
    char* p = ws + off;
    off = (off + bytes + 255) & ~(size_t)255;
    return p;
  };
  half_t* h0   = (half_t*)alloc((size_t)n*64*2);    // init h, f16, stride 64
  half_t* hc   = (half_t*)alloc((size_t)n*128*2);   // [hnew(64) || hres(64)] f16, stride 128
  half_t* hagg0= (half_t*)alloc((size_t)n*64*2);
  half_t* hagg1= (half_t*)alloc((size_t)n*64*2);
  half_t* hsum1= (half_t*)alloc((size_t)n*64*2);
  half_t* z0   = (half_t*)alloc((size_t)n*256*2);
  half_t* z1   = (half_t*)alloc((size_t)n*384*2);
  float* wden = (float*)alloc((size_t)n*4);
  int* deg    = (int*)alloc((size_t)n*4);
  int* tmp    = (int*)alloc((size_t)n*4);
  int* cursor = (int*)alloc((size_t)n*4);
  int* rowptr = (int*)alloc((size_t)(n+1)*4);
  int* col    = (int*)alloc((size_t)E*4);
  int* totals = (int*)alloc(4096);
  half_t* wp0 = (half_t*)alloc((size_t)256*64*2);
  half_t* wp1 = (half_t*)alloc((size_t)128*256*2);
  half_t* wp2 = (half_t*)alloc((size_t)256*64*2);
  half_t* wp3 = (half_t*)alloc((size_t)192*384*2);
  half_t* wp4 = (half_t*)alloc((size_t)384*64*2);

  hipMemsetAsync(deg, 0, (size_t)n*4, stream);

  auto packgrid = [](int K, int M){ return dim3((K*M/8 + 255)/256); };
  pack_w_kernel<<<packgrid(256,64), 256, 0, stream>>>(proj_w, wp0, 256, 64);
  pack_w_kernel<<<packgrid(128,256),256, 0, stream>>>(c0w1, wp1, 128, 256);
  pack_w_kernel<<<packgrid(256,64), 256, 0, stream>>>(c0w2, wp2, 256, 64);
  pack_w_kernel<<<packgrid(192,384),256, 0, stream>>>(c1w1, wp3, 192, 384);
  pack_w_kernel<<<packgrid(384,64), 256, 0, stream>>>(c1w2, wp4, 384, 64);

  const int egrid = (E + 255)/256;
  const int rgrid = (n + 63)/64;
  const int nb1024 = (n + 1023)/1024;

  gemm_kernel<256,64,1,EPI_INIT,false,true><<<rgrid,256,0,stream>>>(
      content,nullptr,nullptr, 256,0,0, wp0, proj_b, h0, 64, node_emb, nid, n);

  // CSR build
  hist_kernel<<<egrid,256,0,stream>>>(dst, deg, E);
  scanA_kernel<<<nb1024,1024,0,stream>>>(deg, tmp, totals, n);
  scanB_kernel<<<1,1024,0,stream>>>(totals, nb1024);
  scanC_kernel<<<(n+256)/256 + 1,256,0,stream>>>(tmp, totals, deg, rowptr, cursor, wden, n, E);
  {
    constexpr int IT = 4;
    int chunks = (E + 256*IT - 1)/(256*IT);
    scatter_kernel<IT><<<chunks*8,256,0,stream>>>(src, dst, cursor, col, E, n);
  }

  // layer 0
  segsum0_kernel<<<(n+3)/4,256,0,stream>>>((const uint*)h0, rowptr, col, wden,
                                           (uint*)hagg0, (uint*)hc, n);
  gemm_kernel<128,256,2,EPI_LRELU,true,true><<<rgrid,256,0,stream>>>(
      h0, hagg0, nullptr, 64,64,0, wp1, c0b1, z0, 256, nullptr, nullptr, n);
  gemm_kernel<256,64,1,EPI_LRELU_L2,true,true><<<rgrid,256,0,stream>>>(
      z0, nullptr, nullptr, 256,0,0, wp2, c0b2, hc, 128, nullptr, nullptr, n);  // hnew -> hc[:,0:64]

  // layer 1
  segsum1_kernel<<<(n+3)/4,256,0,stream>>>((const uint*)hc, rowptr, col, wden,
                                           (uint*)hagg1, (uint*)hsum1, n);
  gemm_kernel<192,384,3,EPI_LRELU,true,true><<<rgrid,256,0,stream>>>(
      hc, hagg1, hsum1, 128,64,64, wp3, c1b1, z1, 384, nullptr, nullptr, n);
  gemm_kernel<384,64,1,EPI_L2,true,false><<<rgrid,256,0,stream>>>(
      z1, nullptr, nullptr, 384,0,0, wp4, c1b2, out, 64, nullptr, nullptr, n);
}

// Round 4
// 427.490 us; speedup vs baseline: 1.7600x; 1.0704x over previous
//
#include <hip/hip_runtime.h>

typedef _Float16 half_t;
typedef half_t h8 __attribute__((ext_vector_type(8)));
typedef float f32x4 __attribute__((ext_vector_type(4)));
typedef unsigned int uint;

__device__ __forceinline__ float lrelu_f(float x){ return x >= 0.f ? x : 0.1f*x; }

__device__ __forceinline__ float2 unpack_h2(uint v){
  half_t lo = __builtin_bit_cast(half_t, (unsigned short)(v & 0xffffu));
  half_t hi = __builtin_bit_cast(half_t, (unsigned short)(v >> 16));
  return make_float2((float)lo, (float)hi);
}
__device__ __forceinline__ uint pack_h2(float a, float b){
  unsigned short lo = __builtin_bit_cast(unsigned short, (half_t)a);
  unsigned short hi = __builtin_bit_cast(unsigned short, (half_t)b);
  return (uint)lo | ((uint)hi << 16);
}

enum { EPI_INIT=0, EPI_LRELU=1, EPI_LRELU_L2=2, EPI_L2=3 };

// ---------- fused weight pre-pack into MFMA B-fragment order (f32 -> f16) ----------
// frag (s, cb): lane l supplies B[k = s*32 + (l>>4)*8 + j][col = cb*16 + (l&15)], j=0..7
__global__ void pack_all_kernel(const float* __restrict__ s0, half_t* __restrict__ d0,
                                const float* __restrict__ s1, half_t* __restrict__ d1,
                                const float* __restrict__ s2, half_t* __restrict__ d2,
                                const float* __restrict__ s3, half_t* __restrict__ d3,
                                const float* __restrict__ s4, half_t* __restrict__ d4){
  int b = blockIdx.x;
  const float* w; half_t* o; int K, M;
  if      (b < 8)  { w=s0; o=d0; K=256; M=64;  }
  else if (b < 24) { w=s1; o=d1; K=128; M=256; b-=8; }
  else if (b < 32) { w=s2; o=d2; K=256; M=64;  b-=24; }
  else if (b < 68) { w=s3; o=d3; K=192; M=384; b-=32; }
  else             { w=s4; o=d4; K=384; M=64;  b-=68; }
  int idx = b*256 + threadIdx.x;
  int total = (K/32)*(M/16)*64;
  if (idx >= total) return;
  int lane = idx & 63;
  int t = idx >> 6;
  int CBn = M/16;
  int cb = t % CBn;
  int s  = t / CBn;
  int k0 = s*32 + (lane>>4)*8;
  int c  = cb*16 + (lane&15);
  #pragma unroll
  for (int j=0;j<8;++j) o[(size_t)idx*8 + j] = (half_t)w[(size_t)(k0+j)*M + c];
}

// ---------- single GEMM (used for init layer only) ----------
template<int K, int MOUT, int EPI>
__global__ __launch_bounds__(256) void gemm_kernel(
  const float* __restrict__ x0, int st0,
  const half_t* __restrict__ wp, const float* __restrict__ bias,
  half_t* __restrict__ outv, int ost,
  const float* __restrict__ emb, const int* __restrict__ nid, int n)
{
  constexpr int KS = K/32;
  constexpr int CB = MOUT/16;
  const int lane = threadIdx.x & 63;
  const int wid  = threadIdx.x >> 6;
  const int row0 = blockIdx.x*64 + wid*16;
  const int arow = row0 + (lane & 15);
  const int arowc = arow < n ? arow : n-1;
  const int khi = (lane>>4)*8;

  f32x4 acc[CB];
  #pragma unroll
  for (int cb=0;cb<CB;++cb) acc[cb] = (f32x4){0.f,0.f,0.f,0.f};

  #pragma unroll
  for (int s=0;s<KS;++s){
    int k0 = s*32 + khi;
    f32x4 a0 = *(const f32x4*)(x0 + (size_t)arowc*st0 + k0);
    f32x4 a1 = *(const f32x4*)(x0 + (size_t)arowc*st0 + k0 + 4);
    h8 af;
    #pragma unroll
    for (int j=0;j<4;++j){ af[j]=(half_t)a0[j]; af[j+4]=(half_t)a1[j]; }
    const h8* wrow = (const h8*)wp + (size_t)(s*CB)*64 + lane;
    #pragma unroll
    for (int cb=0;cb<CB;++cb){
      h8 bf = wrow[cb*64];
      acc[cb] = __builtin_amdgcn_mfma_f32_16x16x32_f16(af, bf, acc[cb], 0,0,0);
    }
  }

  const int cgrp = lane >> 4;
  const int ccol = lane & 15;
  #pragma unroll
  for (int r=0;r<4;++r){
    int R = row0 + cgrp*4 + r;
    int Rc = R < n ? R : n-1;
    if (R < n){
      #pragma unroll
      for (int cb=0;cb<CB;++cb){
        float t = lrelu_f(acc[cb][r] + bias[cb*16+ccol]);
        if constexpr (EPI==EPI_INIT) t += emb[(size_t)(nid[Rc]+1)*64 + cb*16 + ccol];
        outv[(size_t)R*ost + cb*16 + ccol] = (half_t)t;
      }
    }
  }
}

// ---------- fused 2-layer MLP: out = epi2( lrelu(concat(x)@W1+b1) @ W2 + b2 ) ----------
// Stage 1: warps split M1 columns (W1 read once per block). z stored to LDS
// column-major as packed row-pair u32, stride RS=35 (write<=2-way, read conflict-free).
// Stage 2: each warp handles its 16 rows, A-frags via ds_read_b32 + v_perm.
template<int K1, int M1, int M2, int NSRC, int EPI2, bool OUTF16>
__global__ __launch_bounds__(256) void mlp_kernel(
  const half_t* __restrict__ x0, const half_t* __restrict__ x1, const half_t* __restrict__ x2,
  int st0, int st1, int st2,
  const half_t* __restrict__ wp1, const float* __restrict__ b1,
  const half_t* __restrict__ wp2, const float* __restrict__ b2,
  void* __restrict__ outv, int ost, int n)
{
  constexpr int RS  = 35;
  constexpr int KS1 = K1/32, CBT = M1/16, CBW = CBT/4;
  constexpr int KS2 = M1/32, CB2 = M2/16;
  __shared__ uint zc[M1*RS];

  const int lane = threadIdx.x & 63;
  const int wid  = threadIdx.x >> 6;
  const int row0 = blockIdx.x*64;
  const int khi  = (lane>>4)*8;
  const int ccol = lane & 15;
  const int cgrp = lane >> 4;

  // ---- stage 1: z[0:64 rows][wid's 1/4 of M1 cols] ----
  f32x4 acc[4][CBW];
  #pragma unroll
  for (int t=0;t<4;++t)
    #pragma unroll
    for (int cb=0;cb<CBW;++cb) acc[t][cb] = (f32x4){0.f,0.f,0.f,0.f};

  #pragma unroll
  for (int s=0;s<KS1;++s){
    int k0 = s*32 + khi;
    const half_t* p = x0; int st = st0; int koff = k0;
    if constexpr (NSRC>1){
      int isrc = k0 >> 6;
      if constexpr (NSRC>=2){ if (isrc==1){ p=x1; st=st1; } }
      if constexpr (NSRC>=3){ if (isrc==2){ p=x2; st=st2; } }
      koff = k0 & 63;
    }
    h8 af[4];
    #pragma unroll
    for (int t=0;t<4;++t){
      int ar = row0 + t*16 + ccol; if (ar >= n) ar = n-1;
      af[t] = *(const h8*)(p + (size_t)ar*st + koff);
    }
    #pragma unroll
    for (int cb=0;cb<CBW;++cb){
      h8 bf = ((const h8*)wp1)[(size_t)(s*CBT + wid*CBW + cb)*64 + lane];
      #pragma unroll
      for (int t=0;t<4;++t)
        acc[t][cb] = __builtin_amdgcn_mfma_f32_16x16x32_f16(af[t], bf, acc[t][cb], 0,0,0);
    }
  }
  // epilogue 1: bias + lrelu, pack rows (pairs) into col-major LDS
  #pragma unroll
  for (int t=0;t<4;++t){
    #pragma unroll
    for (int cb=0;cb<CBW;++cb){
      int col = wid*(CBW*16) + cb*16 + ccol;
      float bb = b1[col];
      float v0 = lrelu_f(acc[t][cb][0]+bb);
      float v1 = lrelu_f(acc[t][cb][1]+bb);
      float v2 = lrelu_f(acc[t][cb][2]+bb);
      float v3 = lrelu_f(acc[t][cb][3]+bb);
      int idx = col*RS + t*8 + cgrp*2;
      zc[idx]   = pack_h2(v0,v1);
      zc[idx+1] = pack_h2(v2,v3);
    }
  }
  __syncthreads();

  // ---- stage 2: warp owns rows row0 + wid*16 .. +15, all M2 cols ----
  f32x4 acc2[CB2];
  #pragma unroll
  for (int cb=0;cb<CB2;++cb) acc2[cb] = (f32x4){0.f,0.f,0.f,0.f};
  const uint sel = (lane&1) ? 0x07060302u : 0x05040100u;
  const int rp0 = wid*8 + (ccol>>1);

  #pragma unroll
  for (int s=0;s<KS2;++s){
    uint v[8];
    #pragma unroll
    for (int j=0;j<8;++j) v[j] = zc[(s*32 + khi + j)*RS + rp0];
    uint4 u;
    u.x = __builtin_amdgcn_perm(v[1], v[0], sel);
    u.y = __builtin_amdgcn_perm(v[3], v[2], sel);
    u.z = __builtin_amdgcn_perm(v[5], v[4], sel);
    u.w = __builtin_amdgcn_perm(v[7], v[6], sel);
    h8 af2 = __builtin_bit_cast(h8, u);
    #pragma unroll
    for (int cb=0;cb<CB2;++cb){
      h8 bf = ((const h8*)wp2)[(size_t)(s*CB2+cb)*64 + lane];
      acc2[cb] = __builtin_amdgcn_mfma_f32_16x16x32_f16(af2, bf, acc2[cb], 0,0,0);
    }
  }
  // epilogue 2
  #pragma unroll
  for (int r=0;r<4;++r){
    int R = row0 + wid*16 + cgrp*4 + r;
    float vv[CB2];
    #pragma unroll
    for (int cb=0;cb<CB2;++cb){
      float t = acc2[cb][r] + b2[cb*16+ccol];
      if constexpr (EPI2==EPI_LRELU_L2) t = lrelu_f(t);
      vv[cb] = t;
    }
    float sq = 0.f;
    #pragma unroll
    for (int cb=0;cb<CB2;++cb) sq += vv[cb]*vv[cb];
    sq += __shfl_xor(sq,1); sq += __shfl_xor(sq,2);
    sq += __shfl_xor(sq,4); sq += __shfl_xor(sq,8);
    float inv = 1.f / fmaxf(sqrtf(sq), 1e-6f);
    if (R < n){
      #pragma unroll
      for (int cb=0;cb<CB2;++cb){
        float t = vv[cb]*inv;
        if constexpr (OUTF16)
          ((half_t*)outv)[(size_t)R*ost + cb*16 + ccol] = (half_t)t;
        else
          ((float*)outv)[(size_t)R*ost + cb*16 + ccol] = t;
      }
    }
  }
}

// ---------- graph machinery ----------
// XCD-partitioned histogram: atomics stay within one XCD's dst-range.
template<int IT>
__global__ __launch_bounds__(256) void hist_kernel(const int* __restrict__ dst, int* __restrict__ deg,
                                                   int E, int n){
  int part = blockIdx.x & 7;
  long base = (long)(blockIdx.x >> 3) * (256*IT);
  int lo = (int)((long)n * part / 8);
  int hi = (int)((long)n * (part+1) / 8);
  #pragma unroll
  for (int it=0; it<IT; ++it){
    long i = base + it*256 + threadIdx.x;
    if (i < E){
      int d = dst[i];
      if (d >= lo && d < hi) atomicAdd(&deg[d], 1);
    }
  }
}

__global__ __launch_bounds__(1024) void scanA_kernel(const int* __restrict__ deg, int* __restrict__ tmp,
                                                     int* __restrict__ totals, int n){
  __shared__ int sm[1024];
  int i = blockIdx.x*1024 + threadIdx.x;
  int v = (i<n)? deg[i] : 0;
  sm[threadIdx.x]=v;
  __syncthreads();
  for (int off=1; off<1024; off<<=1){
    int t = (threadIdx.x>=(unsigned)off)? sm[threadIdx.x-off] : 0;
    __syncthreads();
    sm[threadIdx.x] += t;
    __syncthreads();
  }
  if (i<n) tmp[i] = sm[threadIdx.x]-v;
  if (threadIdx.x==1023) totals[blockIdx.x]=sm[1023];
}

__global__ __launch_bounds__(1024) void scanB_kernel(int* totals, int nb){
  __shared__ int sm[1024];
  int v = (threadIdx.x < (unsigned)nb) ? totals[threadIdx.x] : 0;
  sm[threadIdx.x]=v;
  __syncthreads();
  for (int off=1; off<1024; off<<=1){
    int t = (threadIdx.x>=(unsigned)off)? sm[threadIdx.x-off] : 0;
    __syncthreads();
    sm[threadIdx.x] += t;
    __syncthreads();
  }
  if (threadIdx.x < (unsigned)nb) totals[threadIdx.x] = sm[threadIdx.x]-v;
}

__global__ void scanC_kernel(const int* __restrict__ tmp, const int* __restrict__ totals,
                             const int* __restrict__ deg, int* __restrict__ rowptr,
                             int* __restrict__ cursor, float* __restrict__ wden, int n, int E){
  int i = blockIdx.x*256 + threadIdx.x;
  if (i > n) return;
  if (i == n){ rowptr[n]=E; return; }
  int v = tmp[i] + totals[i>>10];
  rowptr[i]=v; cursor[i]=v;
  wden[i] = fmaxf((float)deg[i] - 1.f, 1.f);
}

template<int IT>
__global__ __launch_bounds__(256) void scatter_kernel(const int* __restrict__ src, const int* __restrict__ dst,
                               int* __restrict__ cursor, int* __restrict__ col, int E, int n){
  int part = blockIdx.x & 7;
  long base = (long)(blockIdx.x >> 3) * (256*IT);
  int lo = (int)((long)n * part / 8);
  int hi = (int)((long)n * (part+1) / 8);
  #pragma unroll
  for (int it=0; it<IT; ++it){
    long i = base + it*256 + threadIdx.x;
    if (i < E){
      int d = dst[i];
      if (d >= lo && d < hi){
        int pos = atomicAdd(&cursor[d], 1);
        col[pos] = src[i];
      }
    }
  }
}

// layer-0 gather: h rows 128B = 8 lanes x 16B. 8 edge-groups per wave.
__global__ __launch_bounds__(256) void segsum0_kernel(const uint* __restrict__ hu, const int* __restrict__ rowptr,
                               const int* __restrict__ col, const float* __restrict__ wden,
                               uint* __restrict__ hagg, uint* __restrict__ hc, int n){
  int node = blockIdx.x*4 + (threadIdx.x>>6);
  if (node >= n) return;
  int lane = threadIdx.x & 63;
  int g = lane >> 3, l = lane & 7;
  int p0 = rowptr[node], p1 = rowptr[node+1];
  float a[8] = {0,0,0,0,0,0,0,0};
  for (int p = p0 + g; p < p1; p += 8){
    int c = col[p];
    uint4 v = *(const uint4*)(hu + (size_t)c*32 + l*4);
    float2 f0=unpack_h2(v.x), f1=unpack_h2(v.y), f2=unpack_h2(v.z), f3=unpack_h2(v.w);
    a[0]+=f0.x; a[1]+=f0.y; a[2]+=f1.x; a[3]+=f1.y;
    a[4]+=f2.x; a[5]+=f2.y; a[6]+=f3.x; a[7]+=f3.y;
  }
  #pragma unroll
  for (int j=0;j<8;++j){
    a[j] += __shfl_xor(a[j], 8);
    a[j] += __shfl_xor(a[j], 16);
    a[j] += __shfl_xor(a[j], 32);
  }
  uint4 hv4 = *(const uint4*)(hu + (size_t)node*32 + l*4);
  float2 b0=unpack_h2(hv4.x), b1=unpack_h2(hv4.y), b2=unpack_h2(hv4.z), b3=unpack_h2(hv4.w);
  float hv[8] = {b0.x,b0.y,b1.x,b1.y,b2.x,b2.y,b3.x,b3.y};
  float iwd = 1.f / wden[node];
  float sq = 0.f;
  #pragma unroll
  for (int j=0;j<8;++j){ a[j] = (a[j]-hv[j])*iwd; sq += a[j]*a[j]; }
  sq += __shfl_xor(sq,1); sq += __shfl_xor(sq,2); sq += __shfl_xor(sq,4);
  float inv = 1.f / fmaxf(sqrtf(sq), 1e-6f);
  if (g == 0){
    uint4 oa, oh;
    oa.x = pack_h2(a[0],a[1]); oa.y = pack_h2(a[2],a[3]);
    oa.z = pack_h2(a[4],a[5]); oa.w = pack_h2(a[6],a[7]);
    oh.x = pack_h2(a[0]*inv,a[1]*inv); oh.y = pack_h2(a[2]*inv,a[3]*inv);
    oh.z = pack_h2(a[4]*inv,a[5]*inv); oh.w = pack_h2(a[6]*inv,a[7]*inv);
    *(uint4*)(hagg + (size_t)node*32 + l*4) = oa;
    *(uint4*)(hc + (size_t)node*64 + 32 + l*4) = oh;
  }
}

// layer-1 gather: hc rows 256B = 16 lanes x 16B. 4 edge-groups per wave.
__global__ __launch_bounds__(256) void segsum1_kernel(const uint* __restrict__ hcu, const int* __restrict__ rowptr,
                               const int* __restrict__ col, const float* __restrict__ wden,
                               uint* __restrict__ hagg, uint* __restrict__ hsum, int n){
  int node = blockIdx.x*4 + (threadIdx.x>>6);
  if (node >= n) return;
  int lane = threadIdx.x & 63;
  int g = lane >> 4, l = lane & 15;
  int p0 = rowptr[node], p1 = rowptr[node+1];
  float a[8] = {0,0,0,0,0,0,0,0};
  for (int p = p0 + g; p < p1; p += 4){
    int c = col[p];
    uint4 v = *(const uint4*)(hcu + (size_t)c*64 + l*4);
    float2 f0=unpack_h2(v.x), f1=unpack_h2(v.y), f2=unpack_h2(v.z), f3=unpack_h2(v.w);
    a[0]+=f0.x; a[1]+=f0.y; a[2]+=f1.x; a[3]+=f1.y;
    a[4]+=f2.x; a[5]+=f2.y; a[6]+=f3.x; a[7]+=f3.y;
  }
  #pragma unroll
  for (int j=0;j<8;++j){
    a[j] += __shfl_xor(a[j], 16);
    a[j] += __shfl_xor(a[j], 32);
  }
  if (g == 0){
    if (l < 8){
      uint4 hv4 = *(const uint4*)(hcu + (size_t)node*64 + l*4);
      float2 b0=unpack_h2(hv4.x), b1=unpack_h2(hv4.y), b2=unpack_h2(hv4.z), b3=unpack_h2(hv4.w);
      float hv[8] = {b0.x,b0.y,b1.x,b1.y,b2.x,b2.y,b3.x,b3.y};
      float iwd = 1.f / wden[node];
      uint4 o;
      o.x = pack_h2((a[0]-hv[0])*iwd,(a[1]-hv[1])*iwd);
      o.y = pack_h2((a[2]-hv[2])*iwd,(a[3]-hv[3])*iwd);
      o.z = pack_h2((a[4]-hv[4])*iwd,(a[5]-hv[5])*iwd);
      o.w = pack_h2((a[6]-hv[6])*iwd,(a[7]-hv[7])*iwd);
      *(uint4*)(hagg + (size_t)node*32 + l*4) = o;
    } else {
      uint4 o;
      o.x = pack_h2(a[0],a[1]); o.y = pack_h2(a[2],a[3]);
      o.z = pack_h2(a[4],a[5]); o.w = pack_h2(a[6],a[7]);
      *(uint4*)(hsum + (size_t)node*32 + (l-8)*4) = o;
    }
  }
}

extern "C" void kernel_launch(void* const* d_in, const int* in_sizes, int n_in,
                              void* d_out, int out_size, void* d_ws, size_t ws_size,
                              hipStream_t stream){
  const float* content = (const float*)d_in[0];
  const float* node_emb= (const float*)d_in[1];
  const float* proj_w  = (const float*)d_in[2];
  const float* proj_b  = (const float*)d_in[3];
  const float* c0w1 = (const float*)d_in[4];
  const float* c0b1 = (const float*)d_in[5];
  const float* c0w2 = (const float*)d_in[6];
  const float* c0b2 = (const float*)d_in[7];
  const float* c1w1 = (const float*)d_in[8];
  const float* c1b1 = (const float*)d_in[9];
  const float* c1w2 = (const float*)d_in[10];
  const float* c1b2 = (const float*)d_in[11];
  const int* nid = (const int*)d_in[12];
  const int* src = (const int*)d_in[13];
  const int* dst = (const int*)d_in[14];
  float* out = (float*)d_out;
  const int n = in_sizes[12];     // 100000
  const int E = in_sizes[13];     // 1600000

  char* ws = (char*)d_ws;
  size_t off = 0;
  auto alloc = [&](size_t bytes)->char*{
    char* p = ws + off;
    off = (off + bytes + 255) & ~(size_t)255;
    return p;
  };
  half_t* h0   = (half_t*)alloc((size_t)n*64*2);    // init h, stride 64
  half_t* hc   = (half_t*)alloc((size_t)n*128*2);   // [hnew(64) || hres(64)], stride 128
  half_t* hagg0= (half_t*)alloc((size_t)n*64*2);
  half_t* hagg1= (half_t*)alloc((size_t)n*64*2);
  half_t* hsum1= (half_t*)alloc((size_t)n*64*2);
  float* wden = (float*)alloc((size_t)n*4);
  int* deg    = (int*)alloc((size_t)n*4);
  int* tmp    = (int*)alloc((size_t)n*4);
  int* cursor = (int*)alloc((size_t)n*4);
  int* rowptr = (int*)alloc((size_t)(n+1)*4);
  int* col    = (int*)alloc((size_t)E*4);
  int* totals = (int*)alloc(4096);
  half_t* wp0 = (half_t*)alloc((size_t)256*64*2);
  half_t* wp1 = (half_t*)alloc((size_t)128*256*2);
  half_t* wp2 = (half_t*)alloc((size_t)256*64*2);
  half_t* wp3 = (half_t*)alloc((size_t)192*384*2);
  half_t* wp4 = (half_t*)alloc((size_t)384*64*2);

  hipMemsetAsync(deg, 0, (size_t)n*4, stream);

  pack_all_kernel<<<80,256,0,stream>>>(proj_w, wp0, c0w1, wp1, c0w2, wp2, c1w1, wp3, c1w2, wp4);

  const int rgrid = (n + 63)/64;
  const int nb1024 = (n + 1023)/1024;

  // h0 = node_emb[nid+1] + lrelu(content @ proj_w + proj_b)
  gemm_kernel<256,64,EPI_INIT><<<rgrid,256,0,stream>>>(
      content, 256, wp0, proj_b, h0, 64, node_emb, nid, n);

  // CSR build
  {
    constexpr int IT = 8;
    int chunks = (E + 256*IT - 1)/(256*IT);
    hist_kernel<IT><<<chunks*8,256,0,stream>>>(dst, deg, E, n);
  }
  scanA_kernel<<<nb1024,1024,0,stream>>>(deg, tmp, totals, n);
  scanB_kernel<<<1,1024,0,stream>>>(totals, nb1024);
  scanC_kernel<<<(n+256)/256 + 1,256,0,stream>>>(tmp, totals, deg, rowptr, cursor, wden, n, E);
  {
    constexpr int IT = 4;
    int chunks = (E + 256*IT - 1)/(256*IT);
    scatter_kernel<IT><<<chunks*8,256,0,stream>>>(src, dst, cursor, col, E, n);
  }

  // layer 0
  segsum0_kernel<<<(n+3)/4,256,0,stream>>>((const uint*)h0, rowptr, col, wden,
                                           (uint*)hagg0, (uint*)hc, n);
  mlp_kernel<128,256,64,2,EPI_LRELU_L2,true><<<rgrid,256,0,stream>>>(
      h0, hagg0, nullptr, 64,64,0, wp1, c0b1, wp2, c0b2, hc, 128, n);   // hnew -> hc[:,0:64]

  // layer 1
  segsum1_kernel<<<(n+3)/4,256,0,stream>>>((const uint*)hc, rowptr, col, wden,
                                           (uint*)hagg1, (uint*)hsum1, n);
  mlp_kernel<192,384,64,3,EPI_L2,false><<<rgrid,256,0,stream>>>(
      hc, hagg1, hsum1, 128,64,64, wp3, c1b1, wp4, c1b2, out, 64, n);
}

// Round 5
// 381.485 us; speedup vs baseline: 1.9722x; 1.1206x over previous
//
#include <hip/hip_runtime.h>

typedef _Float16 half_t;
typedef half_t h8 __attribute__((ext_vector_type(8)));
typedef float f32x4 __attribute__((ext_vector_type(4)));
typedef unsigned int uint;

__device__ __forceinline__ float lrelu_f(float x){ return x >= 0.f ? x : 0.1f*x; }

__device__ __forceinline__ float2 unpack_h2(uint v){
  half_t lo = __builtin_bit_cast(half_t, (unsigned short)(v & 0xffffu));
  half_t hi = __builtin_bit_cast(half_t, (unsigned short)(v >> 16));
  return make_float2((float)lo, (float)hi);
}
__device__ __forceinline__ uint pack_h2(float a, float b){
  unsigned short lo = __builtin_bit_cast(unsigned short, (half_t)a);
  unsigned short hi = __builtin_bit_cast(unsigned short, (half_t)b);
  return (uint)lo | ((uint)hi << 16);
}

enum { EPI_INIT=0, EPI_LRELU=1, EPI_LRELU_L2=2, EPI_L2=3 };

// ---------- fused weight pre-pack (blocks 0..79) + XCD-partitioned histogram ----------
// pack frag (s, cb): lane l supplies B[k = s*32 + (l>>4)*8 + j][col = cb*16 + (l&15)]
template<int IT>
__global__ void packhist_kernel(const float* __restrict__ s0, half_t* __restrict__ d0,
                                const float* __restrict__ s1, half_t* __restrict__ d1,
                                const float* __restrict__ s2, half_t* __restrict__ d2,
                                const float* __restrict__ s3, half_t* __restrict__ d3,
                                const float* __restrict__ s4, half_t* __restrict__ d4,
                                const int* __restrict__ dst, int* __restrict__ deg, int E, int n){
  int b = blockIdx.x;
  if (b < 80){
    const float* w; half_t* o; int K, M;
    if      (b < 8)  { w=s0; o=d0; K=256; M=64;  }
    else if (b < 24) { w=s1; o=d1; K=128; M=256; b-=8; }
    else if (b < 32) { w=s2; o=d2; K=256; M=64;  b-=24; }
    else if (b < 68) { w=s3; o=d3; K=192; M=384; b-=32; }
    else             { w=s4; o=d4; K=384; M=64;  b-=68; }
    int idx = b*256 + threadIdx.x;
    int total = (K/32)*(M/16)*64;
    if (idx >= total) return;
    int lane = idx & 63;
    int t = idx >> 6;
    int CBn = M/16;
    int cb = t % CBn;
    int s  = t / CBn;
    int k0 = s*32 + (lane>>4)*8;
    int c  = cb*16 + (lane&15);
    #pragma unroll
    for (int j=0;j<8;++j) o[(size_t)idx*8 + j] = (half_t)w[(size_t)(k0+j)*M + c];
    return;
  }
  b -= 80;
  int part = b & 7;
  long base = (long)(b >> 3) * (256*IT);
  int lo = (int)((long)n * part / 8);
  int hi = (int)((long)n * (part+1) / 8);
  #pragma unroll
  for (int it=0; it<IT; ++it){
    long i = base + it*256 + threadIdx.x;
    if (i < E){
      int d = dst[i];
      if (d >= lo && d < hi) atomicAdd(&deg[d], 1);
    }
  }
}

// ---------- single GEMM (init layer) ----------
template<int K, int MOUT, int EPI>
__global__ __launch_bounds__(256) void gemm_kernel(
  const float* __restrict__ x0, int st0,
  const half_t* __restrict__ wp, const float* __restrict__ bias,
  half_t* __restrict__ outv, int ost,
  const float* __restrict__ emb, const int* __restrict__ nid, int n)
{
  constexpr int KS = K/32;
  constexpr int CB = MOUT/16;
  const int lane = threadIdx.x & 63;
  const int wid  = threadIdx.x >> 6;
  const int row0 = blockIdx.x*64 + wid*16;
  const int arow = row0 + (lane & 15);
  const int arowc = arow < n ? arow : n-1;
  const int khi = (lane>>4)*8;

  f32x4 acc[CB];
  #pragma unroll
  for (int cb=0;cb<CB;++cb) acc[cb] = (f32x4){0.f,0.f,0.f,0.f};

  #pragma unroll
  for (int s=0;s<KS;++s){
    int k0 = s*32 + khi;
    f32x4 a0 = *(const f32x4*)(x0 + (size_t)arowc*st0 + k0);
    f32x4 a1 = *(const f32x4*)(x0 + (size_t)arowc*st0 + k0 + 4);
    h8 af;
    #pragma unroll
    for (int j=0;j<4;++j){ af[j]=(half_t)a0[j]; af[j+4]=(half_t)a1[j]; }
    const h8* wrow = (const h8*)wp + (size_t)(s*CB)*64 + lane;
    #pragma unroll
    for (int cb=0;cb<CB;++cb){
      h8 bf = wrow[cb*64];
      acc[cb] = __builtin_amdgcn_mfma_f32_16x16x32_f16(af, bf, acc[cb], 0,0,0);
    }
  }

  const int cgrp = lane >> 4;
  const int ccol = lane & 15;
  #pragma unroll
  for (int r=0;r<4;++r){
    int R = row0 + cgrp*4 + r;
    int Rc = R < n ? R : n-1;
    if (R < n){
      #pragma unroll
      for (int cb=0;cb<CB;++cb){
        float t = lrelu_f(acc[cb][r] + bias[cb*16+ccol]);
        if constexpr (EPI==EPI_INIT) t += emb[(size_t)(nid[Rc]+1)*64 + cb*16 + ccol];
        outv[(size_t)R*ost + cb*16 + ccol] = (half_t)t;
      }
    }
  }
}

// ---------- fused 2-layer MLP, 32 rows/block ----------
// Stage 1: 4 warps split M1 cols; z -> LDS col-major packed row-pairs (stride 17).
// Stage 2: warps split (row-half rt, k-half kh); kh=1 writes partial C to LDS,
// kh=0 adds + fused epilogue (l2norm).
template<int K1, int M1, int M2, int NSRC, int EPI2, bool OUTF16>
__global__ __launch_bounds__(256,4) void mlp_kernel(
  const half_t* __restrict__ x0, const half_t* __restrict__ x1, const half_t* __restrict__ x2,
  int st0, int st1, int st2,
  const half_t* __restrict__ wp1, const float* __restrict__ b1,
  const half_t* __restrict__ wp2, const float* __restrict__ b2,
  void* __restrict__ outv, int ost, int n)
{
  constexpr int RS  = 17;                    // u32 per z-col: 16 row-pairs + 1 pad
  constexpr int KS1 = K1/32, CBT = M1/16, CBW = CBT/4;
  constexpr int KS2 = M1/32, CB2 = M2/16;
  constexpr int RED = 65;                    // f32 stride of reduce buffer
  __shared__ uint  zc[M1*RS];
  __shared__ float red[2*16*RED];

  const int lane = threadIdx.x & 63;
  const int wid  = threadIdx.x >> 6;
  const int row0 = blockIdx.x*32;
  const int khi  = (lane>>4)*8;
  const int ccol = lane & 15;
  const int cgrp = lane >> 4;

  // ---- stage 1: z[0:32 rows][wid's 1/4 of M1 cols] ----
  f32x4 acc[2][CBW];
  #pragma unroll
  for (int t=0;t<2;++t)
    #pragma unroll
    for (int cb=0;cb<CBW;++cb) acc[t][cb] = (f32x4){0.f,0.f,0.f,0.f};

  #pragma unroll
  for (int s=0;s<KS1;++s){
    int k0 = s*32 + khi;
    const half_t* p = x0; int st = st0; int koff = k0;
    if constexpr (NSRC>1){
      int isrc = k0 >> 6;
      if constexpr (NSRC>=2){ if (isrc==1){ p=x1; st=st1; } }
      if constexpr (NSRC>=3){ if (isrc==2){ p=x2; st=st2; } }
      koff = k0 & 63;
    }
    h8 af[2];
    #pragma unroll
    for (int t=0;t<2;++t){
      int ar = row0 + t*16 + ccol; if (ar >= n) ar = n-1;
      af[t] = *(const h8*)(p + (size_t)ar*st + koff);
    }
    #pragma unroll
    for (int cb=0;cb<CBW;++cb){
      h8 bf = ((const h8*)wp1)[(size_t)(s*CBT + wid*CBW + cb)*64 + lane];
      #pragma unroll
      for (int t=0;t<2;++t)
        acc[t][cb] = __builtin_amdgcn_mfma_f32_16x16x32_f16(af[t], bf, acc[t][cb], 0,0,0);
    }
  }
  // epilogue 1: bias + lrelu, pack row-pairs into col-major LDS
  #pragma unroll
  for (int t=0;t<2;++t){
    #pragma unroll
    for (int cb=0;cb<CBW;++cb){
      int col = wid*(CBW*16) + cb*16 + ccol;
      float bb = b1[col];
      float v0 = lrelu_f(acc[t][cb][0]+bb);
      float v1 = lrelu_f(acc[t][cb][1]+bb);
      float v2 = lrelu_f(acc[t][cb][2]+bb);
      float v3 = lrelu_f(acc[t][cb][3]+bb);
      int idx = col*RS + t*8 + cgrp*2;
      zc[idx]   = pack_h2(v0,v1);
      zc[idx+1] = pack_h2(v2,v3);
    }
  }
  __syncthreads();

  // ---- stage 2: warp (rt = row-half, kh = k-half) ----
  const int rt = wid & 1, kh = wid >> 1;
  f32x4 acc2[CB2];
  #pragma unroll
  for (int cb=0;cb<CB2;++cb) acc2[cb] = (f32x4){0.f,0.f,0.f,0.f};
  const uint sel = (lane&1) ? 0x07060302u : 0x05040100u;
  const int rp0 = rt*8 + (ccol>>1);

  #pragma unroll
  for (int si=0;si<KS2/2;++si){
    int s = kh*(KS2/2) + si;
    uint v[8];
    #pragma unroll
    for (int j=0;j<8;++j) v[j] = zc[(s*32 + khi + j)*RS + rp0];
    uint4 u;
    u.x = __builtin_amdgcn_perm(v[1], v[0], sel);
    u.y = __builtin_amdgcn_perm(v[3], v[2], sel);
    u.z = __builtin_amdgcn_perm(v[5], v[4], sel);
    u.w = __builtin_amdgcn_perm(v[7], v[6], sel);
    h8 af2 = __builtin_bit_cast(h8, u);
    #pragma unroll
    for (int cb=0;cb<CB2;++cb){
      h8 bf = ((const h8*)wp2)[(size_t)(s*CB2+cb)*64 + lane];
      acc2[cb] = __builtin_amdgcn_mfma_f32_16x16x32_f16(af2, bf, acc2[cb], 0,0,0);
    }
  }
  if (kh == 1){
    #pragma unroll
    for (int cb=0;cb<CB2;++cb)
      #pragma unroll
      for (int r=0;r<4;++r)
        red[(rt*16 + cgrp*4 + r)*RED + cb*16 + ccol] = acc2[cb][r];
  }
  __syncthreads();
  if (kh == 0){
    #pragma unroll
    for (int r=0;r<4;++r){
      int R = row0 + rt*16 + cgrp*4 + r;
      float vv[CB2];
      #pragma unroll
      for (int cb=0;cb<CB2;++cb){
        float t = acc2[cb][r] + red[(rt*16 + cgrp*4 + r)*RED + cb*16 + ccol] + b2[cb*16+ccol];
        if constexpr (EPI2==EPI_LRELU_L2) t = lrelu_f(t);
        vv[cb] = t;
      }
      float sq = 0.f;
      #pragma unroll
      for (int cb=0;cb<CB2;++cb) sq += vv[cb]*vv[cb];
      sq += __shfl_xor(sq,1); sq += __shfl_xor(sq,2);
      sq += __shfl_xor(sq,4); sq += __shfl_xor(sq,8);
      float inv = 1.f / fmaxf(sqrtf(sq), 1e-6f);
      if (R < n){
        #pragma unroll
        for (int cb=0;cb<CB2;++cb){
          float t = vv[cb]*inv;
          if constexpr (OUTF16)
            ((half_t*)outv)[(size_t)R*ost + cb*16 + ccol] = (half_t)t;
          else
            ((float*)outv)[(size_t)R*ost + cb*16 + ccol] = t;
        }
      }
    }
  }
}

// ---------- graph machinery ----------
__global__ __launch_bounds__(1024) void scanA_kernel(const int* __restrict__ deg, int* __restrict__ tmp,
                                                     int* __restrict__ totals, int n){
  __shared__ int sm[1024];
  int i = blockIdx.x*1024 + threadIdx.x;
  int v = (i<n)? deg[i] : 0;
  sm[threadIdx.x]=v;
  __syncthreads();
  for (int off=1; off<1024; off<<=1){
    int t = (threadIdx.x>=(unsigned)off)? sm[threadIdx.x-off] : 0;
    __syncthreads();
    sm[threadIdx.x] += t;
    __syncthreads();
  }
  if (i<n) tmp[i] = sm[threadIdx.x]-v;
  if (threadIdx.x==1023) totals[blockIdx.x]=sm[1023];
}

__global__ __launch_bounds__(1024) void scanB_kernel(int* totals, int nb){
  __shared__ int sm[1024];
  int v = (threadIdx.x < (unsigned)nb) ? totals[threadIdx.x] : 0;
  sm[threadIdx.x]=v;
  __syncthreads();
  for (int off=1; off<1024; off<<=1){
    int t = (threadIdx.x>=(unsigned)off)? sm[threadIdx.x-off] : 0;
    __syncthreads();
    sm[threadIdx.x] += t;
    __syncthreads();
  }
  if (threadIdx.x < (unsigned)nb) totals[threadIdx.x] = sm[threadIdx.x]-v;
}

__global__ void scanC_kernel(const int* __restrict__ tmp, const int* __restrict__ totals,
                             const int* __restrict__ deg, int* __restrict__ rowptr,
                             int* __restrict__ cursor, float* __restrict__ wden, int n, int E){
  int i = blockIdx.x*256 + threadIdx.x;
  if (i > n) return;
  if (i == n){ rowptr[n]=E; return; }
  int v = tmp[i] + totals[i>>10];
  rowptr[i]=v; cursor[i]=v;
  wden[i] = fmaxf((float)deg[i] - 1.f, 1.f);
}

template<int IT>
__global__ __launch_bounds__(256) void scatter_kernel(const int* __restrict__ src, const int* __restrict__ dst,
                               int* __restrict__ cursor, int* __restrict__ col, int E, int n){
  int part = blockIdx.x & 7;
  long base = (long)(blockIdx.x >> 3) * (256*IT);
  int lo = (int)((long)n * part / 8);
  int hi = (int)((long)n * (part+1) / 8);
  #pragma unroll
  for (int it=0; it<IT; ++it){
    long i = base + it*256 + threadIdx.x;
    if (i < E){
      int d = dst[i];
      if (d >= lo && d < hi){
        int pos = atomicAdd(&cursor[d], 1);
        col[pos] = src[i];
      }
    }
  }
}

// layer-0 gather: h rows 128B = 8 lanes x 16B. 8 edge-groups per wave.
__global__ __launch_bounds__(256) void segsum0_kernel(const uint* __restrict__ hu, const int* __restrict__ rowptr,
                               const int* __restrict__ col, const float* __restrict__ wden,
                               uint* __restrict__ hagg, uint* __restrict__ hc, int n){
  int node = blockIdx.x*4 + (threadIdx.x>>6);
  if (node >= n) return;
  int lane = threadIdx.x & 63;
  int g = lane >> 3, l = lane & 7;
  int p0 = rowptr[node], p1 = rowptr[node+1];
  float a[8] = {0,0,0,0,0,0,0,0};
  for (int p = p0 + g; p < p1; p += 8){
    int c = col[p];
    uint4 v = *(const uint4*)(hu + (size_t)c*32 + l*4);
    float2 f0=unpack_h2(v.x), f1=unpack_h2(v.y), f2=unpack_h2(v.z), f3=unpack_h2(v.w);
    a[0]+=f0.x; a[1]+=f0.y; a[2]+=f1.x; a[3]+=f1.y;
    a[4]+=f2.x; a[5]+=f2.y; a[6]+=f3.x; a[7]+=f3.y;
  }
  #pragma unroll
  for (int j=0;j<8;++j){
    a[j] += __shfl_xor(a[j], 8);
    a[j] += __shfl_xor(a[j], 16);
    a[j] += __shfl_xor(a[j], 32);
  }
  uint4 hv4 = *(const uint4*)(hu + (size_t)node*32 + l*4);
  float2 b0=unpack_h2(hv4.x), b1=unpack_h2(hv4.y), b2=unpack_h2(hv4.z), b3=unpack_h2(hv4.w);
  float hv[8] = {b0.x,b0.y,b1.x,b1.y,b2.x,b2.y,b3.x,b3.y};
  float iwd = 1.f / wden[node];
  float sq = 0.f;
  #pragma unroll
  for (int j=0;j<8;++j){ a[j] = (a[j]-hv[j])*iwd; sq += a[j]*a[j]; }
  sq += __shfl_xor(sq,1); sq += __shfl_xor(sq,2); sq += __shfl_xor(sq,4);
  float inv = 1.f / fmaxf(sqrtf(sq), 1e-6f);
  if (g == 0){
    uint4 oa, oh;
    oa.x = pack_h2(a[0],a[1]); oa.y = pack_h2(a[2],a[3]);
    oa.z = pack_h2(a[4],a[5]); oa.w = pack_h2(a[6],a[7]);
    oh.x = pack_h2(a[0]*inv,a[1]*inv); oh.y = pack_h2(a[2]*inv,a[3]*inv);
    oh.z = pack_h2(a[4]*inv,a[5]*inv); oh.w = pack_h2(a[6]*inv,a[7]*inv);
    *(uint4*)(hagg + (size_t)node*32 + l*4) = oa;
    *(uint4*)(hc + (size_t)node*64 + 32 + l*4) = oh;
  }
}

// layer-1 gather: hc rows 256B = 16 lanes x 16B. 4 edge-groups per wave.
__global__ __launch_bounds__(256) void segsum1_kernel(const uint* __restrict__ hcu, const int* __restrict__ rowptr,
                               const int* __restrict__ col, const float* __restrict__ wden,
                               uint* __restrict__ hagg, uint* __restrict__ hsum, int n){
  int node = blockIdx.x*4 + (threadIdx.x>>6);
  if (node >= n) return;
  int lane = threadIdx.x & 63;
  int g = lane >> 4, l = lane & 15;
  int p0 = rowptr[node], p1 = rowptr[node+1];
  float a[8] = {0,0,0,0,0,0,0,0};
  for (int p = p0 + g; p < p1; p += 4){
    int c = col[p];
    uint4 v = *(const uint4*)(hcu + (size_t)c*64 + l*4);
    float2 f0=unpack_h2(v.x), f1=unpack_h2(v.y), f2=unpack_h2(v.z), f3=unpack_h2(v.w);
    a[0]+=f0.x; a[1]+=f0.y; a[2]+=f1.x; a[3]+=f1.y;
    a[4]+=f2.x; a[5]+=f2.y; a[6]+=f3.x; a[7]+=f3.y;
  }
  #pragma unroll
  for (int j=0;j<8;++j){
    a[j] += __shfl_xor(a[j], 16);
    a[j] += __shfl_xor(a[j], 32);
  }
  if (g == 0){
    if (l < 8){
      uint4 hv4 = *(const uint4*)(hcu + (size_t)node*64 + l*4);
      float2 b0=unpack_h2(hv4.x), b1=unpack_h2(hv4.y), b2=unpack_h2(hv4.z), b3=unpack_h2(hv4.w);
      float hv[8] = {b0.x,b0.y,b1.x,b1.y,b2.x,b2.y,b3.x,b3.y};
      float iwd = 1.f / wden[node];
      uint4 o;
      o.x = pack_h2((a[0]-hv[0])*iwd,(a[1]-hv[1])*iwd);
      o.y = pack_h2((a[2]-hv[2])*iwd,(a[3]-hv[3])*iwd);
      o.z = pack_h2((a[4]-hv[4])*iwd,(a[5]-hv[5])*iwd);
      o.w = pack_h2((a[6]-hv[6])*iwd,(a[7]-hv[7])*iwd);
      *(uint4*)(hagg + (size_t)node*32 + l*4) = o;
    } else {
      uint4 o;
      o.x = pack_h2(a[0],a[1]); o.y = pack_h2(a[2],a[3]);
      o.z = pack_h2(a[4],a[5]); o.w = pack_h2(a[6],a[7]);
      *(uint4*)(hsum + (size_t)node*32 + (l-8)*4) = o;
    }
  }
}

extern "C" void kernel_launch(void* const* d_in, const int* in_sizes, int n_in,
                              void* d_out, int out_size, void* d_ws, size_t ws_size,
                              hipStream_t stream){
  const float* content = (const float*)d_in[0];
  const float* node_emb= (const float*)d_in[1];
  const float* proj_w  = (const float*)d_in[2];
  const float* proj_b  = (const float*)d_in[3];
  const float* c0w1 = (const float*)d_in[4];
  const float* c0b1 = (const float*)d_in[5];
  const float* c0w2 = (const float*)d_in[6];
  const float* c0b2 = (const float*)d_in[7];
  const float* c1w1 = (const float*)d_in[8];
  const float* c1b1 = (const float*)d_in[9];
  const float* c1w2 = (const float*)d_in[10];
  const float* c1b2 = (const float*)d_in[11];
  const int* nid = (const int*)d_in[12];
  const int* src = (const int*)d_in[13];
  const int* dst = (const int*)d_in[14];
  float* out = (float*)d_out;
  const int n = in_sizes[12];     // 100000
  const int E = in_sizes[13];     // 1600000

  char* ws = (char*)d_ws;
  size_t off = 0;
  auto alloc = [&](size_t bytes)->char*{
    char* p = ws + off;
    off = (off + bytes + 255) & ~(size_t)255;
    return p;
  };
  half_t* h0   = (half_t*)alloc((size_t)n*64*2);    // init h, stride 64
  half_t* hc   = (half_t*)alloc((size_t)n*128*2);   // [hnew(64) || hres(64)], stride 128
  half_t* hagg0= (half_t*)alloc((size_t)n*64*2);
  half_t* hagg1= (half_t*)alloc((size_t)n*64*2);
  half_t* hsum1= (half_t*)alloc((size_t)n*64*2);
  float* wden = (float*)alloc((size_t)n*4);
  int* deg    = (int*)alloc((size_t)n*4);
  int* tmp    = (int*)alloc((size_t)n*4);
  int* cursor = (int*)alloc((size_t)n*4);
  int* rowptr = (int*)alloc((size_t)(n+1)*4);
  int* col    = (int*)alloc((size_t)E*4);
  int* totals = (int*)alloc(4096);
  half_t* wp0 = (half_t*)alloc((size_t)256*64*2);
  half_t* wp1 = (half_t*)alloc((size_t)128*256*2);
  half_t* wp2 = (half_t*)alloc((size_t)256*64*2);
  half_t* wp3 = (half_t*)alloc((size_t)192*384*2);
  half_t* wp4 = (half_t*)alloc((size_t)384*64*2);

  hipMemsetAsync(deg, 0, (size_t)n*4, stream);

  // pack (80 blocks) + histogram (XCD-partitioned) in one dispatch
  {
    constexpr int IT = 8;
    int chunks = (E + 256*IT - 1)/(256*IT);
    packhist_kernel<IT><<<80 + chunks*8,256,0,stream>>>(
        proj_w, wp0, c0w1, wp1, c0w2, wp2, c1w1, wp3, c1w2, wp4, dst, deg, E, n);
  }

  const int rgrid = (n + 63)/64;
  const int mgrid = (n + 31)/32;
  const int nb1024 = (n + 1023)/1024;

  // h0 = node_emb[nid+1] + lrelu(content @ proj_w + proj_b)
  gemm_kernel<256,64,EPI_INIT><<<rgrid,256,0,stream>>>(
      content, 256, wp0, proj_b, h0, 64, node_emb, nid, n);

  scanA_kernel<<<nb1024,1024,0,stream>>>(deg, tmp, totals, n);
  scanB_kernel<<<1,1024,0,stream>>>(totals, nb1024);
  scanC_kernel<<<(n+256)/256 + 1,256,0,stream>>>(tmp, totals, deg, rowptr, cursor, wden, n, E);
  {
    constexpr int IT = 4;
    int chunks = (E + 256*IT - 1)/(256*IT);
    scatter_kernel<IT><<<chunks*8,256,0,stream>>>(src, dst, cursor, col, E, n);
  }

  // layer 0
  segsum0_kernel<<<(n+3)/4,256,0,stream>>>((const uint*)h0, rowptr, col, wden,
                                           (uint*)hagg0, (uint*)hc, n);
  mlp_kernel<128,256,64,2,EPI_LRELU_L2,true><<<mgrid,256,0,stream>>>(
      h0, hagg0, nullptr, 64,64,0, wp1, c0b1, wp2, c0b2, hc, 128, n);   // hnew -> hc[:,0:64]

  // layer 1
  segsum1_kernel<<<(n+3)/4,256,0,stream>>>((const uint*)hc, rowptr, col, wden,
                                           (uint*)hagg1, (uint*)hsum1, n);
  mlp_kernel<192,384,64,3,EPI_L2,false><<<mgrid,256,0,stream>>>(
      hc, hagg1, hsum1, 128,64,64, wp3, c1b1, wp4, c1b2, out, 64, n);
}